// Round 8
// baseline (166.131 us; speedup 1.0000x reference)
//
#include <hip/hip_runtime.h>
#include <math.h>

#define E_TYPES 20
#define NBLK 2
#define NANG 7
#define CS 384
#define CH 128
#define N_TOK (8 * 2048)
#define TOK 96
#define MFRAG 3                              // m-frags per wave (wave tile 48x32)
#define TPB_MAIN 512
#define KC 128
#define MAX_TILES (N_TOK / TOK + E_TYPES)   // 170 + 20 = 190 (provable upper bound)
#define NPREP 64

// ---- workspace: int control region ----
#define HIST_OFF 0           // 64 x 20 per-block histograms

// ---- workspace: fragment-packed split-bf16 weights (bytes) ----
// 1KB block = 64 lanes x 16B; element (n,k): lane = (n&15)|((k>>3&3)<<4), j=k&7
#define WT1_OFF (256 * 1024)                       // phase-1 concat [768x128] per e
#define WT1_SZ  (20 * 8 * 24 * 2048)               // e x nt(8) x kb(24) x (hi1KB+lo1KB)
#define WTR_OFF (WT1_OFF + WT1_SZ)                 // residual: e x m4(4) x nt(8) x kb(4)
// total end ~13.4 MB

typedef __attribute__((ext_vector_type(8))) short bfrag;
typedef __attribute__((ext_vector_type(4))) float f32x4;
typedef unsigned short (*arr136)[136];

__device__ __forceinline__ void split_bf16(float x, unsigned short& h, unsigned short& l) {
    unsigned int u = __float_as_uint(x);
    unsigned int hb = (u + 0x7FFFu + ((u >> 16) & 1u)) & 0xFFFF0000u;
    h = (unsigned short)(hb >> 16);
    float r = x - __uint_as_float(hb);
    unsigned int v = __float_as_uint(r);
    l = (unsigned short)((v + 0x7FFFu + ((v >> 16) & 1u)) >> 16);
}

// prep1: blocks [0,1600) convert weights to fragment-packed split-bf16;
// blocks [1600,1664) build the per-block token histogram.
__global__ void prep1(const float* __restrict__ Win, const float* __restrict__ Winit,
                      const float* __restrict__ Wb1, const float* __restrict__ Wb2,
                      const int* __restrict__ aatype, int* __restrict__ wsI,
                      unsigned short* __restrict__ wt) {
    __shared__ int lh[E_TYPES];
    int bid = blockIdx.x;
    int t = threadIdx.x;
    if (bid >= 1600) {   // histogram part
        int b2 = bid - 1600;
        if (t < E_TYPES) lh[t] = 0;
        __syncthreads();
        int idx = b2 * 256 + t;
        if (idx < N_TOK) atomicAdd(&lh[aatype[idx]], 1);
        __syncthreads();
        if (t < E_TYPES) wsI[HIST_OFF + b2 * E_TYPES + t] = lh[t];
        return;
    }
    int gid = bid * 256 + t;
    unsigned short h[8], l[8];
    if (gid < 245760) {          // phase-1 weights: 20*8*24 blocks x 64 lanes
        int lane = gid & 63;
        int bi = gid >> 6;
        int kb = bi % 24;
        int r = bi / 24;
        int nt = r & 7, e = r >> 3;
        int n = nt * 16 + (lane & 15);
        int k0 = kb * 32 + (lane >> 4) * 8;
        #pragma unroll
        for (int j = 0; j < 8; j++) {
            int k = k0 + j;
            float x = (k < CS) ? Win[((size_t)e * CS + k) * CH + n]
                               : Winit[((size_t)e * CS + (k - CS)) * CH + n];
            split_bf16(x, h[j], l[j]);
        }
        unsigned short* dst = wt + (WT1_OFF / 2) + (size_t)bi * 1024 + lane * 8;
        *(bfrag*)dst = *(bfrag*)h;
        *(bfrag*)(dst + 512) = *(bfrag*)l;
    } else {                     // residual weights: 20*4*8*4 blocks x 64 lanes
        gid -= 245760;
        int lane = gid & 63;
        int bi = gid >> 6;       // 0..2559
        int kb = bi & 3;
        int nt = (bi >> 2) & 7;
        int m4 = (bi >> 5) & 3;
        int e = bi >> 7;
        int b = m4 >> 1;
        const float* W = (m4 & 1) ? Wb2 : Wb1;
        int n = nt * 16 + (lane & 15);
        int k0 = kb * 32 + (lane >> 4) * 8;
        #pragma unroll
        for (int j = 0; j < 8; j++) {
            int k = k0 + j;
            float x = W[(((size_t)e * NBLK + b) * CH + k) * CH + n];
            split_bf16(x, h[j], l[j]);
        }
        unsigned short* dst = wt + (WTR_OFF / 2) + (size_t)bi * 1024 + lane * 8;
        *(bfrag*)dst = *(bfrag*)h;
        *(bfrag*)(dst + 512) = *(bfrag*)l;
    }
}

#define MFMA(a, b, c) __builtin_amdgcn_mfma_f32_16x16x32_bf16((a), (b), (c), 0, 0, 0)

// Load the 8 weight fragments (bh ks0..3, bl ks0..3) for one stage/n-frag.
#define LOADW(DST, BASEPTR) do {                                   \
    const bfrag* _p = (BASEPTR);                                   \
    DST[0] = _p[0];   DST[1] = _p[128];                            \
    DST[2] = _p[256]; DST[3] = _p[384];                            \
    DST[4] = _p[64];  DST[5] = _p[192];                            \
    DST[6] = _p[320]; DST[7] = _p[448];                            \
} while (0)

// One K=128 stage for this wave's 48x32 tile: 4 ks x 3 m-frags; each
// A-fragment read now feeds BOTH n-frags (6 MFMAs per hi/lo pair) —
// halving LDS read traffic per MFMA vs the old 1-n-strip mapping.
#define MFMA_STAGE(WAH, WAL, C0, C1, A0, B0, A1, B1) do {          \
    _Pragma("unroll")                                              \
    for (int ks = 0; ks < 4; ks++) {                               \
        int kl = ks * 32 + quad * 8;                               \
        _Pragma("unroll")                                          \
        for (int m = 0; m < MFRAG; m++) {                          \
            bfrag ah = *(const bfrag*)&WAH[mrow + m * 16 + lane15][kl]; \
            bfrag al = *(const bfrag*)&WAL[mrow + m * 16 + lane15][kl]; \
            A0[m] = MFMA(ah, C0[ks], A0[m]);                       \
            B0[m] = MFMA(ah, C0[4 + ks], B0[m]);                   \
            B0[m] = MFMA(al, C0[ks], B0[m]);                       \
            A1[m] = MFMA(ah, C1[ks], A1[m]);                       \
            B1[m] = MFMA(ah, C1[4 + ks], B1[m]);                   \
            B1[m] = MFMA(al, C1[ks], B1[m]);                       \
        }                                                          \
    }                                                              \
} while (0)

// Write relu of this wave's tile (3 m-frags x 2 n-frags, C layout) as
// split-bf16 A for the next GEMM. Waves cover disjoint 48x32 tiles.
#define WRITE_H(WAH, WAL, S0, S1) do {                             \
    _Pragma("unroll")                                              \
    for (int m = 0; m < MFRAG; m++)                                \
    {                                                              \
        _Pragma("unroll")                                          \
        for (int rr = 0; rr < 4; rr++) {                           \
            int row = mrow + m * 16 + quad * 4 + rr;               \
            unsigned short hh, ll;                                 \
            split_bf16(fmaxf(S0[m][rr], 0.f), hh, ll);             \
            WAH[row][nc0] = hh;                                    \
            WAL[row][nc0] = ll;                                    \
            split_bf16(fmaxf(S1[m][rr], 0.f), hh, ll);             \
            WAH[row][nc1] = hh;                                    \
            WAL[row][nc1] = ll;                                    \
        }                                                          \
    }                                                              \
} while (0)

// Stage one 16-float activation segment (relu + split) into LDS.
__device__ __forceinline__ void stage_seg(arr136 WAH, arr136 WAL, int row, int col,
                                          float4 a, float4 b, float4 c, float4 d) {
    float xv[16] = {a.x, a.y, a.z, a.w, b.x, b.y, b.z, b.w,
                    c.x, c.y, c.z, c.w, d.x, d.y, d.z, d.w};
    unsigned short h8[8], l8[8];
    #pragma unroll
    for (int j = 0; j < 8; j++) split_bf16(fmaxf(xv[j], 0.f), h8[j], l8[j]);
    *(bfrag*)&WAH[row][col] = *(bfrag*)h8;
    *(bfrag*)&WAL[row][col] = *(bfrag*)l8;
    #pragma unroll
    for (int j = 0; j < 8; j++) split_bf16(fmaxf(xv[8 + j], 0.f), h8[j], l8[j]);
    *(bfrag*)&WAH[row][col + 8] = *(bfrag*)h8;
    *(bfrag*)&WAL[row][col + 8] = *(bfrag*)l8;
}

// TOK=96, 8 waves as (2 m-groups x 4 n-groups); wave tile = 48 rows x 32
// cols (3 m-frags x 2 n-frags). Grid <= 190 <= 256 (r6 lever preserved).
__global__ __launch_bounds__(TPB_MAIN, 2)
void angle_main(const float* __restrict__ s, const float* __restrict__ si,
                const float* __restrict__ b_in, const float* __restrict__ b_init2,
                const float* __restrict__ bb1, const float* __restrict__ bb2,
                const float* __restrict__ Wout, const float* __restrict__ b_out,
                const int* __restrict__ aatype,
                const int* __restrict__ wsI, const unsigned short* __restrict__ wt,
                float* __restrict__ out)
{
    // LDS pool: two (Ah,Al) buffers of [96][136] u16; epilogue Hf/Of overlap.
    #define ABUF 26112
    __shared__ __align__(16) char pool[4 * ABUF];
    __shared__ int ptok[TOK];
    __shared__ int cntS[E_TYPES];

    arr136 AH0 = (arr136)(pool);
    arr136 AL0 = (arr136)(pool + ABUF);
    arr136 AH1 = (arr136)(pool + 2 * ABUF);
    arr136 AL1 = (arr136)(pool + 3 * ABUF);
    float (*Hf)[132] = (float (*)[132])(pool);            // 96*132*4 = 50688 <= 2*ABUF
    float (*Of)[16]  = (float (*)[16])(pool + 2 * ABUF);  // 6KB

    int t = threadIdx.x;
    int w = t >> 6, lane = t & 63;
    int lane15 = lane & 15, quad = lane >> 4;
    int mw = w >> 2, nw = w & 3;              // wave tile coords
    int mrow = mw * 48;
    int nc0 = nw * 32 + lane15;
    int nc1 = nc0 + 16;
    int nt0 = nw * 2, nt1 = nw * 2 + 1;       // weight n-tile indices

    // XCD-chunked bijective swizzle (e-sorted tiles -> per-XCD L2 residency).
    int bid = blockIdx.x;
    const int q = MAX_TILES >> 3, r = MAX_TILES & 7;   // 23, 6
    int xcd = bid & 7, sub = bid >> 3;
    int tile = (xcd < r ? xcd * (q + 1) : r * (q + 1) + (xcd - r) * q) + sub;

    // wave0: per-type totals from the 64x20 chunk histograms
    if (w == 0 && lane < E_TYPES) {
        int c = 0;
        #pragma unroll
        for (int b = 0; b < NPREP; b++) c += wsI[HIST_OFF + b * E_TYPES + lane];
        cntS[lane] = c;
    }
    __syncthreads();

    int pos = tile * TOK;
    int e = -1, poff_e = 0;
    {
        int accT = 0;
        #pragma unroll
        for (int ee = 0; ee < E_TYPES; ee++) {
            int pad = ((cntS[ee] + TOK - 1) / TOK) * TOK;   // TOK not pow2
            if (e < 0 && pos < accT + pad) { e = ee; poff_e = accT; }
            accT += pad;
        }
        if (pos >= accT) return;     // uniform exit (all waves agree)
    }
    int pos_in = pos - poff_e;
    int n = cntS[e] - pos_in; if (n > TOK) n = TOK;

    const bfrag* wt1 = (const bfrag*)((const char*)wt + WT1_OFF);
    const bfrag* wtr = (const bfrag*)((const char*)wt + WTR_OFF);
    size_t wb0 = (size_t)(e * 8 + nt0) * 24;
    size_t wb1 = (size_t)(e * 8 + nt1) * 24;

    // Early issue: stage-0 weights (both n-frags) + all bias values.
    bfrag Wr0a[8], Wr0b[8], Wr1a[8], Wr1b[8];
    LOADW(Wr0a, wt1 + wb0 * 128 + lane);
    LOADW(Wr0b, wt1 + wb1 * 128 + lane);
    float bv_in0 = b_in[e * CH + nc0] + b_init2[e * CH + nc0];
    float bv_in1 = b_in[e * CH + nc1] + b_init2[e * CH + nc1];
    float bvb1a0 = bb1[(e * NBLK + 0) * CH + nc0], bvb1a1 = bb1[(e * NBLK + 0) * CH + nc1];
    float bvb1b0 = bb1[(e * NBLK + 1) * CH + nc0], bvb1b1 = bb1[(e * NBLK + 1) * CH + nc1];
    float bvb2a0 = bb2[(e * NBLK + 0) * CH + nc0], bvb2a1 = bb2[(e * NBLK + 0) * CH + nc1];
    float bvb2b0 = bb2[(e * NBLK + 1) * CH + nc0], bvb2b1 = bb2[(e * NBLK + 1) * CH + nc1];

    // wave0: rank-scan aatype -> ptok (tokens with rank [pos_in, pos_in+n))
    if (w == 0) {
        int hb = wsI[HIST_OFF + lane * E_TYPES + e];
        int inc = hb;
        #pragma unroll
        for (int d = 1; d < 64; d <<= 1) { int v = __shfl_up(inc, d); if (lane >= d) inc += v; }
        int pre = inc - hb;
        unsigned long long mle = __ballot(pre <= pos_in);
        int cb = 63 - __clzll(mle);
        int running = __shfl(pre, cb);
        int base = cb * 256;
        int lim = pos_in + n;
        while (running < lim && base < N_TOK) {
            const int4 a4 = *(const int4*)&aatype[base + lane * 4];
            int m0 = (a4.x == e), m1 = (a4.y == e), m2 = (a4.z == e), m3 = (a4.w == e);
            int c = m0 + m1 + m2 + m3;
            int incl = c;
            #pragma unroll
            for (int d = 1; d < 64; d <<= 1) { int v = __shfl_up(incl, d); if (lane >= d) incl += v; }
            int rk = running + incl - c;
            int tk = base + lane * 4;
            if (m0) { if (rk >= pos_in && rk < lim) ptok[rk - pos_in] = tk;     rk++; }
            if (m1) { if (rk >= pos_in && rk < lim) ptok[rk - pos_in] = tk + 1; rk++; }
            if (m2) { if (rk >= pos_in && rk < lim) ptok[rk - pos_in] = tk + 2; rk++; }
            if (m3) { if (rk >= pos_in && rk < lim) ptok[rk - pos_in] = tk + 3; rk++; }
            running += __shfl(incl, 63);
            base += 256;
        }
        int t0v = ptok[0];
        for (int i = n + lane; i < TOK; i += 64) ptok[i] = t0v;   // pad w/ dup token
    }
    __syncthreads();

    // ---- phase 1: h = [relu(s) relu(si)] @ [Win;Winit] + biases, K=768 ----
    // Staging: 768 segs (96 rows x 8) over 512 threads; threads 0-255 take a
    // second seg (waves 0-3, wave-uniform). One chunk prefetched ahead.
    int srow0 = t >> 3;
    int scol0 = (t & 7) * 16;
    bool has2 = (t < TOK * 8 - TPB_MAIN);    // t < 256
    int srow1 = srow0 + 64;
    size_t ro0 = (size_t)ptok[srow0] * CS + scol0;
    size_t ro1 = has2 ? ((size_t)ptok[srow1] * CS + scol0) : ro0;
    float4 p0 = *(const float4*)(s + ro0);
    float4 p1 = *(const float4*)(s + ro0 + 4);
    float4 p2 = *(const float4*)(s + ro0 + 8);
    float4 p3 = *(const float4*)(s + ro0 + 12);
    float4 q0, q1, q2, q3;
    if (has2) {
        q0 = *(const float4*)(s + ro1);
        q1 = *(const float4*)(s + ro1 + 4);
        q2 = *(const float4*)(s + ro1 + 8);
        q3 = *(const float4*)(s + ro1 + 12);
    }

    f32x4 aA0[MFRAG], aB0[MFRAG], aA1[MFRAG], aB1[MFRAG];
    #pragma unroll
    for (int m = 0; m < MFRAG; m++) {
        aA0[m] = (f32x4){bv_in0, bv_in0, bv_in0, bv_in0};
        aA1[m] = (f32x4){bv_in1, bv_in1, bv_in1, bv_in1};
        aB0[m] = (f32x4){0.f, 0.f, 0.f, 0.f};
        aB1[m] = aB0[m];
    }

    #pragma unroll
    for (int c = 0; c < 6; c++) {
        arr136 WAH = (c & 1) ? AH1 : AH0;
        arr136 WAL = (c & 1) ? AL1 : AL0;
        stage_seg(WAH, WAL, srow0, scol0, p0, p1, p2, p3);
        if (has2) stage_seg(WAH, WAL, srow1, scol0, q0, q1, q2, q3);
        if (c < 5) {   // prefetch next chunk activations
            const float* src = (c + 1 < 3) ? s : si;
            int kb0 = ((c + 1 < 3) ? (c + 1) : (c - 2)) * KC;
            p0 = *(const float4*)(src + ro0 + kb0);
            p1 = *(const float4*)(src + ro0 + kb0 + 4);
            p2 = *(const float4*)(src + ro0 + kb0 + 8);
            p3 = *(const float4*)(src + ro0 + kb0 + 12);
            if (has2) {
                q0 = *(const float4*)(src + ro1 + kb0);
                q1 = *(const float4*)(src + ro1 + kb0 + 4);
                q2 = *(const float4*)(src + ro1 + kb0 + 8);
                q3 = *(const float4*)(src + ro1 + kb0 + 12);
            }
        }
        __syncthreads();
        if ((c & 1) == 0) {
            if (c < 5) {
                LOADW(Wr1a, wt1 + (wb0 + (c + 1) * 4) * 128 + lane);
                LOADW(Wr1b, wt1 + (wb1 + (c + 1) * 4) * 128 + lane);
            }
            MFMA_STAGE(AH0, AL0, Wr0a, Wr0b, aA0, aB0, aA1, aB1);
        } else {
            if (c == 5) {
                LOADW(Wr0a, wtr + (((size_t)(e * 4) * 8 + nt0) * 4) * 128 + lane);
                LOADW(Wr0b, wtr + (((size_t)(e * 4) * 8 + nt1) * 4) * 128 + lane);
            } else {
                LOADW(Wr0a, wt1 + (wb0 + (c + 1) * 4) * 128 + lane);
                LOADW(Wr0b, wt1 + (wb1 + (c + 1) * 4) * 128 + lane);
            }
            MFMA_STAGE(AH1, AL1, Wr1a, Wr1b, aA0, aB0, aA1, aB1);
        }
    }

    // ---- residual blocks: 4 GEMMs, one barrier each ----
    f32x4 h0[MFRAG], h1[MFRAG];
    #pragma unroll
    for (int m = 0; m < MFRAG; m++) { h0[m] = aA0[m] + aB0[m]; h1[m] = aA1[m] + aB1[m]; }
    WRITE_H(AH0, AL0, h0, h1);
    __syncthreads();

    f32x4 rA0[MFRAG], rB0[MFRAG], rA1[MFRAG], rB1[MFRAG];
    // g0: a1 = relu(h) @ W1[0] + bb1[0]
    #pragma unroll
    for (int m = 0; m < MFRAG; m++) {
        rA0[m] = (f32x4){bvb1a0, bvb1a0, bvb1a0, bvb1a0};
        rA1[m] = (f32x4){bvb1a1, bvb1a1, bvb1a1, bvb1a1};
        rB0[m] = (f32x4){0.f, 0.f, 0.f, 0.f};
        rB1[m] = rB0[m];
    }
    LOADW(Wr1a, wtr + (((size_t)(e * 4 + 1) * 8 + nt0) * 4) * 128 + lane);
    LOADW(Wr1b, wtr + (((size_t)(e * 4 + 1) * 8 + nt1) * 4) * 128 + lane);
    MFMA_STAGE(AH0, AL0, Wr0a, Wr0b, rA0, rB0, rA1, rB1);
    #pragma unroll
    for (int m = 0; m < MFRAG; m++) { rA0[m] += rB0[m]; rA1[m] += rB1[m]; }
    WRITE_H(AH1, AL1, rA0, rA1);
    __syncthreads();

    // g1: h += relu(a1) @ W2[0] + bb2[0]
    #pragma unroll
    for (int m = 0; m < MFRAG; m++) {
        rA0[m] = (f32x4){bvb2a0, bvb2a0, bvb2a0, bvb2a0};
        rA1[m] = (f32x4){bvb2a1, bvb2a1, bvb2a1, bvb2a1};
        rB0[m] = (f32x4){0.f, 0.f, 0.f, 0.f};
        rB1[m] = rB0[m];
    }
    LOADW(Wr0a, wtr + (((size_t)(e * 4 + 2) * 8 + nt0) * 4) * 128 + lane);
    LOADW(Wr0b, wtr + (((size_t)(e * 4 + 2) * 8 + nt1) * 4) * 128 + lane);
    MFMA_STAGE(AH1, AL1, Wr1a, Wr1b, rA0, rB0, rA1, rB1);
    #pragma unroll
    for (int m = 0; m < MFRAG; m++) { h0[m] += rA0[m] + rB0[m]; h1[m] += rA1[m] + rB1[m]; }
    WRITE_H(AH0, AL0, h0, h1);
    __syncthreads();

    // g2: a1 = relu(h) @ W1[1] + bb1[1]
    #pragma unroll
    for (int m = 0; m < MFRAG; m++) {
        rA0[m] = (f32x4){bvb1b0, bvb1b0, bvb1b0, bvb1b0};
        rA1[m] = (f32x4){bvb1b1, bvb1b1, bvb1b1, bvb1b1};
        rB0[m] = (f32x4){0.f, 0.f, 0.f, 0.f};
        rB1[m] = rB0[m];
    }
    LOADW(Wr1a, wtr + (((size_t)(e * 4 + 3) * 8 + nt0) * 4) * 128 + lane);
    LOADW(Wr1b, wtr + (((size_t)(e * 4 + 3) * 8 + nt1) * 4) * 128 + lane);
    MFMA_STAGE(AH0, AL0, Wr0a, Wr0b, rA0, rB0, rA1, rB1);
    #pragma unroll
    for (int m = 0; m < MFRAG; m++) { rA0[m] += rB0[m]; rA1[m] += rB1[m]; }
    WRITE_H(AH1, AL1, rA0, rA1);
    __syncthreads();

    // g3: h += relu(a1) @ W2[1] + bb2[1]
    #pragma unroll
    for (int m = 0; m < MFRAG; m++) {
        rA0[m] = (f32x4){bvb2b0, bvb2b0, bvb2b0, bvb2b0};
        rA1[m] = (f32x4){bvb2b1, bvb2b1, bvb2b1, bvb2b1};
        rB0[m] = (f32x4){0.f, 0.f, 0.f, 0.f};
        rB1[m] = rB0[m];
    }
    MFMA_STAGE(AH1, AL1, Wr1a, Wr1b, rA0, rB0, rA1, rB1);
    #pragma unroll
    for (int m = 0; m < MFRAG; m++) { h0[m] += rA0[m] + rB0[m]; h1[m] += rA1[m] + rB1[m]; }

    // ---- epilogue: relu(h) fp32 -> Hf (buf0 region; g3 readers used buf1) ----
    #pragma unroll
    for (int m = 0; m < MFRAG; m++)
    {
        #pragma unroll
        for (int rr = 0; rr < 4; rr++) {
            int row = mrow + m * 16 + quad * 4 + rr;
            Hf[row][nc0] = fmaxf(h0[m][rr], 0.f);
            Hf[row][nc1] = fmaxf(h1[m][rr], 0.f);
        }
    }
    __syncthreads();

    // ---- out = relu(h) @ Wout + b_out (128 -> 14), 4-way partials ----
    const float* WoutE = Wout + (size_t)e * CH * (NANG * 2);
    const float* boutE = b_out + (size_t)e * (NANG * 2);
    for (int idx = t; idx < n * (NANG * 2); idx += TPB_MAIN) {
        int i = idx / (NANG * 2);
        int o = idx - i * (NANG * 2);
        float v0 = boutE[o], v1 = 0.f, v2 = 0.f, v3 = 0.f;
        #pragma unroll 4
        for (int k = 0; k < CH; k += 4) {
            v0 = fmaf(Hf[i][k],     WoutE[(size_t)k * (NANG * 2) + o],       v0);
            v1 = fmaf(Hf[i][k + 1], WoutE[(size_t)(k + 1) * (NANG * 2) + o], v1);
            v2 = fmaf(Hf[i][k + 2], WoutE[(size_t)(k + 2) * (NANG * 2) + o], v2);
            v3 = fmaf(Hf[i][k + 3], WoutE[(size_t)(k + 3) * (NANG * 2) + o], v3);
        }
        Of[i][o] = (v0 + v1) + (v2 + v3);
    }
    __syncthreads();

    // ---- pair-normalize and store ----
    for (int idx = t; idx < n * NANG; idx += TPB_MAIN) {
        int i = idx / NANG;
        int a = idx - i * NANG;
        float x = Of[i][2 * a];
        float y = Of[i][2 * a + 1];
        float nr = fmaxf(sqrtf(x * x + y * y), 1e-12f);
        size_t base = (size_t)ptok[i] * (NANG * 2) + 2 * a;
        out[base]     = x / nr;
        out[base + 1] = y / nr;
    }
}

extern "C" void kernel_launch(void* const* d_in, const int* in_sizes, int n_in,
                              void* d_out, int out_size, void* d_ws, size_t ws_size,
                              hipStream_t stream) {
    const float* s       = (const float*)d_in[0];
    const float* s_init  = (const float*)d_in[1];
    const int*   aatype  = (const int*)d_in[2];
    const float* Win     = (const float*)d_in[3];
    const float* b_in    = (const float*)d_in[4];
    const float* Winit   = (const float*)d_in[5];
    const float* b_init2 = (const float*)d_in[6];
    const float* Wb1     = (const float*)d_in[7];
    const float* bb1     = (const float*)d_in[8];
    const float* Wb2     = (const float*)d_in[9];
    const float* bb2     = (const float*)d_in[10];
    const float* Wout    = (const float*)d_in[11];
    const float* b_out   = (const float*)d_in[12];
    int* wsI = (int*)d_ws;
    unsigned short* wt = (unsigned short*)d_ws;
    float* out = (float*)d_out;

    hipLaunchKernelGGL(prep1, dim3(1664), dim3(256), 0, stream,
                       Win, Winit, Wb1, Wb2, aatype, wsI, wt);
    hipLaunchKernelGGL(angle_main, dim3(MAX_TILES), dim3(TPB_MAIN), 0, stream,
                       s, s_init, b_in, b_init2, bb1, bb2, Wout, b_out,
                       aatype, wsI, wt, out);
}

// Round 9
// 159.431 us; speedup vs baseline: 1.0420x; 1.0420x over previous
//
#include <hip/hip_runtime.h>
#include <math.h>

#define E_TYPES 20
#define NBLK 2
#define NANG 7
#define CS 384
#define CH 128
#define N_TOK (8 * 2048)
#define TOK 96
#define MFRAG 3                              // m-frags per wave (wave tile 48x32)
#define TPB_MAIN 512
#define KC 128
#define MAX_TILES (N_TOK / TOK + E_TYPES)   // 170 + 20 = 190 (provable upper bound)
#define NPREP 64

// ---- workspace: int control region ----
#define HIST_OFF 0           // 64 x 20 per-block histograms

// ---- workspace: fragment-packed split-bf16 weights (bytes) ----
// 1KB block = 64 lanes x 16B; element (n,k): lane = (n&15)|((k>>3&3)<<4), j=k&7
#define WT1_OFF (256 * 1024)                       // phase-1 concat [768x128] per e
#define WT1_SZ  (20 * 8 * 24 * 2048)               // e x nt(8) x kb(24) x (hi1KB+lo1KB)
#define WTR_OFF (WT1_OFF + WT1_SZ)                 // residual: e x m4(4) x nt(8) x kb(4)
// total end ~13.4 MB

typedef __attribute__((ext_vector_type(8))) short bfrag;
typedef __attribute__((ext_vector_type(4))) float f32x4;
typedef unsigned short (*arr136)[136];

__device__ __forceinline__ void split_bf16(float x, unsigned short& h, unsigned short& l) {
    unsigned int u = __float_as_uint(x);
    unsigned int hb = (u + 0x7FFFu + ((u >> 16) & 1u)) & 0xFFFF0000u;
    h = (unsigned short)(hb >> 16);
    float r = x - __uint_as_float(hb);
    unsigned int v = __float_as_uint(r);
    l = (unsigned short)((v + 0x7FFFu + ((v >> 16) & 1u)) >> 16);
}

// prep1: blocks [0,1600) convert weights to fragment-packed split-bf16;
// blocks [1600,1664) build the per-block token histogram.
__global__ void prep1(const float* __restrict__ Win, const float* __restrict__ Winit,
                      const float* __restrict__ Wb1, const float* __restrict__ Wb2,
                      const int* __restrict__ aatype, int* __restrict__ wsI,
                      unsigned short* __restrict__ wt) {
    __shared__ int lh[E_TYPES];
    int bid = blockIdx.x;
    int t = threadIdx.x;
    if (bid >= 1600) {   // histogram part
        int b2 = bid - 1600;
        if (t < E_TYPES) lh[t] = 0;
        __syncthreads();
        int idx = b2 * 256 + t;
        if (idx < N_TOK) atomicAdd(&lh[aatype[idx]], 1);
        __syncthreads();
        if (t < E_TYPES) wsI[HIST_OFF + b2 * E_TYPES + t] = lh[t];
        return;
    }
    int gid = bid * 256 + t;
    unsigned short h[8], l[8];
    if (gid < 245760) {          // phase-1 weights: 20*8*24 blocks x 64 lanes
        int lane = gid & 63;
        int bi = gid >> 6;
        int kb = bi % 24;
        int r = bi / 24;
        int nt = r & 7, e = r >> 3;
        int n = nt * 16 + (lane & 15);
        int k0 = kb * 32 + (lane >> 4) * 8;
        #pragma unroll
        for (int j = 0; j < 8; j++) {
            int k = k0 + j;
            float x = (k < CS) ? Win[((size_t)e * CS + k) * CH + n]
                               : Winit[((size_t)e * CS + (k - CS)) * CH + n];
            split_bf16(x, h[j], l[j]);
        }
        unsigned short* dst = wt + (WT1_OFF / 2) + (size_t)bi * 1024 + lane * 8;
        *(bfrag*)dst = *(bfrag*)h;
        *(bfrag*)(dst + 512) = *(bfrag*)l;
    } else {                     // residual weights: 20*4*8*4 blocks x 64 lanes
        gid -= 245760;
        int lane = gid & 63;
        int bi = gid >> 6;       // 0..2559
        int kb = bi & 3;
        int nt = (bi >> 2) & 7;
        int m4 = (bi >> 5) & 3;
        int e = bi >> 7;
        int b = m4 >> 1;
        const float* W = (m4 & 1) ? Wb2 : Wb1;
        int n = nt * 16 + (lane & 15);
        int k0 = kb * 32 + (lane >> 4) * 8;
        #pragma unroll
        for (int j = 0; j < 8; j++) {
            int k = k0 + j;
            float x = W[(((size_t)e * NBLK + b) * CH + k) * CH + n];
            split_bf16(x, h[j], l[j]);
        }
        unsigned short* dst = wt + (WTR_OFF / 2) + (size_t)bi * 1024 + lane * 8;
        *(bfrag*)dst = *(bfrag*)h;
        *(bfrag*)(dst + 512) = *(bfrag*)l;
    }
}

#define MFMA(a, b, c) __builtin_amdgcn_mfma_f32_16x16x32_bf16((a), (b), (c), 0, 0, 0)

// MFMAs for one k-slice: 3 m-frags x 2 n-frags x (hi/lo triple) = 18 MFMA.
// Accumulation order per acc chain identical to prior rounds (bitwise-same).
#define KS_MFMA(WAH, WAL, KS, BHA, BLA, BHB, BLB, A0, B0, A1, B1) do { \
    int kl = (KS) * 32 + quad * 8;                                     \
    _Pragma("unroll")                                                  \
    for (int m = 0; m < MFRAG; m++) {                                  \
        bfrag ah = *(const bfrag*)&WAH[mrow + m * 16 + lane15][kl];    \
        bfrag al = *(const bfrag*)&WAL[mrow + m * 16 + lane15][kl];    \
        A0[m] = MFMA(ah, BHA, A0[m]);                                  \
        B0[m] = MFMA(ah, BLA, B0[m]);                                  \
        B0[m] = MFMA(al, BHA, B0[m]);                                  \
        A1[m] = MFMA(ah, BHB, A1[m]);                                  \
        B1[m] = MFMA(ah, BLB, B1[m]);                                  \
        B1[m] = MFMA(al, BHB, B1[m]);                                  \
    }                                                                  \
} while (0)

// One K=128 stage, k-slice weight pipeline (spill fix vs r8's 128-reg
// stage double-buffer): Wp0..3 hold ks0 (loaded across the barrier);
// ks1-3's 12 fragments are issued at stage entry and covered by ks0's
// 18 MFMAs; Wp is reloaded for the NEXT stage right after ks0. Peak
// live weight regs: 64 VGPR transient (vs 128 persistent in r8).
#define MFMA_STAGE(WAH, WAL, PA, PB, NPA, NPB, A0, B0, A1, B1) do {    \
    bfrag w1a = (PA)[128], w1l = (PA)[192], w1b = (PB)[128], w1m = (PB)[192]; \
    bfrag w2a = (PA)[256], w2l = (PA)[320], w2b = (PB)[256], w2m = (PB)[320]; \
    bfrag w3a = (PA)[384], w3l = (PA)[448], w3b = (PB)[384], w3m = (PB)[448]; \
    KS_MFMA(WAH, WAL, 0, Wp0, Wp1, Wp2, Wp3, A0, B0, A1, B1);          \
    Wp0 = (NPA)[0]; Wp1 = (NPA)[64]; Wp2 = (NPB)[0]; Wp3 = (NPB)[64];  \
    KS_MFMA(WAH, WAL, 1, w1a, w1l, w1b, w1m, A0, B0, A1, B1);          \
    KS_MFMA(WAH, WAL, 2, w2a, w2l, w2b, w2m, A0, B0, A1, B1);          \
    KS_MFMA(WAH, WAL, 3, w3a, w3l, w3b, w3m, A0, B0, A1, B1);          \
} while (0)

// Write relu of this wave's tile (3 m-frags x 2 n-frags, C layout) as
// split-bf16 A for the next GEMM. Waves cover disjoint 48x32 tiles.
#define WRITE_H(WAH, WAL, S0, S1) do {                             \
    _Pragma("unroll")                                              \
    for (int m = 0; m < MFRAG; m++)                                \
    {                                                              \
        _Pragma("unroll")                                          \
        for (int rr = 0; rr < 4; rr++) {                           \
            int row = mrow + m * 16 + quad * 4 + rr;               \
            unsigned short hh, ll;                                 \
            split_bf16(fmaxf(S0[m][rr], 0.f), hh, ll);             \
            WAH[row][nc0] = hh;                                    \
            WAL[row][nc0] = ll;                                    \
            split_bf16(fmaxf(S1[m][rr], 0.f), hh, ll);             \
            WAH[row][nc1] = hh;                                    \
            WAL[row][nc1] = ll;                                    \
        }                                                          \
    }                                                              \
} while (0)

// Stage one 16-float activation segment (relu + split) into LDS.
__device__ __forceinline__ void stage_seg(arr136 WAH, arr136 WAL, int row, int col,
                                          float4 a, float4 b, float4 c, float4 d) {
    float xv[16] = {a.x, a.y, a.z, a.w, b.x, b.y, b.z, b.w,
                    c.x, c.y, c.z, c.w, d.x, d.y, d.z, d.w};
    unsigned short h8[8], l8[8];
    #pragma unroll
    for (int j = 0; j < 8; j++) split_bf16(fmaxf(xv[j], 0.f), h8[j], l8[j]);
    *(bfrag*)&WAH[row][col] = *(bfrag*)h8;
    *(bfrag*)&WAL[row][col] = *(bfrag*)l8;
    #pragma unroll
    for (int j = 0; j < 8; j++) split_bf16(fmaxf(xv[8 + j], 0.f), h8[j], l8[j]);
    *(bfrag*)&WAH[row][col + 8] = *(bfrag*)h8;
    *(bfrag*)&WAL[row][col + 8] = *(bfrag*)l8;
}

// TOK=96, 8 waves as (2 m-groups x 4 n-groups); wave tile = 48 rows x 32
// cols (3 m-frags x 2 n-frags). Grid <= 190 <= 256 (r6 lever preserved).
__global__ __launch_bounds__(TPB_MAIN, 2)
void angle_main(const float* __restrict__ s, const float* __restrict__ si,
                const float* __restrict__ b_in, const float* __restrict__ b_init2,
                const float* __restrict__ bb1, const float* __restrict__ bb2,
                const float* __restrict__ Wout, const float* __restrict__ b_out,
                const int* __restrict__ aatype,
                const int* __restrict__ wsI, const unsigned short* __restrict__ wt,
                float* __restrict__ out)
{
    // LDS pool: two (Ah,Al) buffers of [96][136] u16; epilogue Hf/Of overlap.
    #define ABUF 26112
    __shared__ __align__(16) char pool[4 * ABUF];
    __shared__ int ptok[TOK];
    __shared__ int cntS[E_TYPES];

    arr136 AH0 = (arr136)(pool);
    arr136 AL0 = (arr136)(pool + ABUF);
    arr136 AH1 = (arr136)(pool + 2 * ABUF);
    arr136 AL1 = (arr136)(pool + 3 * ABUF);
    float (*Hf)[132] = (float (*)[132])(pool);            // 96*132*4 = 50688 <= 2*ABUF
    float (*Of)[16]  = (float (*)[16])(pool + 2 * ABUF);  // 6KB

    int t = threadIdx.x;
    int w = t >> 6, lane = t & 63;
    int lane15 = lane & 15, quad = lane >> 4;
    int mw = w >> 2, nw = w & 3;              // wave tile coords
    int mrow = mw * 48;
    int nc0 = nw * 32 + lane15;
    int nc1 = nc0 + 16;
    int nt0 = nw * 2, nt1 = nw * 2 + 1;       // weight n-tile indices

    // XCD-chunked bijective swizzle (e-sorted tiles -> per-XCD L2 residency).
    int bid = blockIdx.x;
    const int q = MAX_TILES >> 3, r = MAX_TILES & 7;   // 23, 6
    int xcd = bid & 7, sub = bid >> 3;
    int tile = (xcd < r ? xcd * (q + 1) : r * (q + 1) + (xcd - r) * q) + sub;

    // wave0: per-type totals from the 64x20 chunk histograms
    if (w == 0 && lane < E_TYPES) {
        int c = 0;
        #pragma unroll
        for (int b = 0; b < NPREP; b++) c += wsI[HIST_OFF + b * E_TYPES + lane];
        cntS[lane] = c;
    }
    __syncthreads();

    int pos = tile * TOK;
    int e = -1, poff_e = 0;
    {
        int accT = 0;
        #pragma unroll
        for (int ee = 0; ee < E_TYPES; ee++) {
            int pad = ((cntS[ee] + TOK - 1) / TOK) * TOK;   // TOK not pow2
            if (e < 0 && pos < accT + pad) { e = ee; poff_e = accT; }
            accT += pad;
        }
        if (pos >= accT) return;     // uniform exit (all waves agree)
    }
    int pos_in = pos - poff_e;
    int n = cntS[e] - pos_in; if (n > TOK) n = TOK;

    const bfrag* wt1 = (const bfrag*)((const char*)wt + WT1_OFF);
    const bfrag* wtr = (const bfrag*)((const char*)wt + WTR_OFF);
    size_t wb0 = (size_t)(e * 8 + nt0) * 24;
    size_t wb1 = (size_t)(e * 8 + nt1) * 24;

    // Early issue: stage-0 ks0 weights + all bias values.
    bfrag Wp0, Wp1, Wp2, Wp3;
    {
        const bfrag* pa0 = wt1 + wb0 * 128 + lane;
        const bfrag* pb0 = wt1 + wb1 * 128 + lane;
        Wp0 = pa0[0]; Wp1 = pa0[64]; Wp2 = pb0[0]; Wp3 = pb0[64];
    }
    float bv_in0 = b_in[e * CH + nc0] + b_init2[e * CH + nc0];
    float bv_in1 = b_in[e * CH + nc1] + b_init2[e * CH + nc1];
    float bvb1a0 = bb1[(e * NBLK + 0) * CH + nc0], bvb1a1 = bb1[(e * NBLK + 0) * CH + nc1];
    float bvb1b0 = bb1[(e * NBLK + 1) * CH + nc0], bvb1b1 = bb1[(e * NBLK + 1) * CH + nc1];
    float bvb2a0 = bb2[(e * NBLK + 0) * CH + nc0], bvb2a1 = bb2[(e * NBLK + 0) * CH + nc1];
    float bvb2b0 = bb2[(e * NBLK + 1) * CH + nc0], bvb2b1 = bb2[(e * NBLK + 1) * CH + nc1];

    // wave0: rank-scan aatype -> ptok (tokens with rank [pos_in, pos_in+n))
    if (w == 0) {
        int hb = wsI[HIST_OFF + lane * E_TYPES + e];
        int inc = hb;
        #pragma unroll
        for (int d = 1; d < 64; d <<= 1) { int v = __shfl_up(inc, d); if (lane >= d) inc += v; }
        int pre = inc - hb;
        unsigned long long mle = __ballot(pre <= pos_in);
        int cb = 63 - __clzll(mle);
        int running = __shfl(pre, cb);
        int base = cb * 256;
        int lim = pos_in + n;
        while (running < lim && base < N_TOK) {
            const int4 a4 = *(const int4*)&aatype[base + lane * 4];
            int m0 = (a4.x == e), m1 = (a4.y == e), m2 = (a4.z == e), m3 = (a4.w == e);
            int c = m0 + m1 + m2 + m3;
            int incl = c;
            #pragma unroll
            for (int d = 1; d < 64; d <<= 1) { int v = __shfl_up(incl, d); if (lane >= d) incl += v; }
            int rk = running + incl - c;
            int tk = base + lane * 4;
            if (m0) { if (rk >= pos_in && rk < lim) ptok[rk - pos_in] = tk;     rk++; }
            if (m1) { if (rk >= pos_in && rk < lim) ptok[rk - pos_in] = tk + 1; rk++; }
            if (m2) { if (rk >= pos_in && rk < lim) ptok[rk - pos_in] = tk + 2; rk++; }
            if (m3) { if (rk >= pos_in && rk < lim) ptok[rk - pos_in] = tk + 3; rk++; }
            running += __shfl(incl, 63);
            base += 256;
        }
        int t0v = ptok[0];
        for (int i = n + lane; i < TOK; i += 64) ptok[i] = t0v;   // pad w/ dup token
    }
    __syncthreads();

    // ---- phase 1: h = [relu(s) relu(si)] @ [Win;Winit] + biases, K=768 ----
    // Staging: 768 segs (96 rows x 8) over 512 threads; threads 0-255 take a
    // second seg (waves 0-3, wave-uniform). One chunk prefetched ahead.
    int srow0 = t >> 3;
    int scol0 = (t & 7) * 16;
    bool has2 = (t < TOK * 8 - TPB_MAIN);    // t < 256
    int srow1 = srow0 + 64;
    size_t ro0 = (size_t)ptok[srow0] * CS + scol0;
    size_t ro1 = has2 ? ((size_t)ptok[srow1] * CS + scol0) : ro0;
    float4 p0 = *(const float4*)(s + ro0);
    float4 p1 = *(const float4*)(s + ro0 + 4);
    float4 p2 = *(const float4*)(s + ro0 + 8);
    float4 p3 = *(const float4*)(s + ro0 + 12);
    float4 q0, q1, q2, q3;
    if (has2) {
        q0 = *(const float4*)(s + ro1);
        q1 = *(const float4*)(s + ro1 + 4);
        q2 = *(const float4*)(s + ro1 + 8);
        q3 = *(const float4*)(s + ro1 + 12);
    }

    f32x4 aA0[MFRAG], aB0[MFRAG], aA1[MFRAG], aB1[MFRAG];
    #pragma unroll
    for (int m = 0; m < MFRAG; m++) {
        aA0[m] = (f32x4){bv_in0, bv_in0, bv_in0, bv_in0};
        aA1[m] = (f32x4){bv_in1, bv_in1, bv_in1, bv_in1};
        aB0[m] = (f32x4){0.f, 0.f, 0.f, 0.f};
        aB1[m] = aB0[m];
    }

    #pragma unroll
    for (int c = 0; c < 6; c++) {
        arr136 WAH = (c & 1) ? AH1 : AH0;
        arr136 WAL = (c & 1) ? AL1 : AL0;
        stage_seg(WAH, WAL, srow0, scol0, p0, p1, p2, p3);
        if (has2) stage_seg(WAH, WAL, srow1, scol0, q0, q1, q2, q3);
        if (c < 5) {   // prefetch next chunk activations
            const float* src = (c + 1 < 3) ? s : si;
            int kb0 = ((c + 1 < 3) ? (c + 1) : (c - 2)) * KC;
            p0 = *(const float4*)(src + ro0 + kb0);
            p1 = *(const float4*)(src + ro0 + kb0 + 4);
            p2 = *(const float4*)(src + ro0 + kb0 + 8);
            p3 = *(const float4*)(src + ro0 + kb0 + 12);
            if (has2) {
                q0 = *(const float4*)(src + ro1 + kb0);
                q1 = *(const float4*)(src + ro1 + kb0 + 4);
                q2 = *(const float4*)(src + ro1 + kb0 + 8);
                q3 = *(const float4*)(src + ro1 + kb0 + 12);
            }
        }
        __syncthreads();
        const bfrag* pa = wt1 + (wb0 + c * 4) * 128 + lane;
        const bfrag* pb = wt1 + (wb1 + c * 4) * 128 + lane;
        const bfrag* npa = (c < 5) ? wt1 + (wb0 + (c + 1) * 4) * 128 + lane
                                   : wtr + (((size_t)(e * 4) * 8 + nt0) * 4) * 128 + lane;
        const bfrag* npb = (c < 5) ? wt1 + (wb1 + (c + 1) * 4) * 128 + lane
                                   : wtr + (((size_t)(e * 4) * 8 + nt1) * 4) * 128 + lane;
        if ((c & 1) == 0) MFMA_STAGE(AH0, AL0, pa, pb, npa, npb, aA0, aB0, aA1, aB1);
        else              MFMA_STAGE(AH1, AL1, pa, pb, npa, npb, aA0, aB0, aA1, aB1);
    }

    // ---- residual blocks: 4 GEMMs, one barrier each ----
    f32x4 h0[MFRAG], h1[MFRAG];
    #pragma unroll
    for (int m = 0; m < MFRAG; m++) { h0[m] = aA0[m] + aB0[m]; h1[m] = aA1[m] + aB1[m]; }
    WRITE_H(AH0, AL0, h0, h1);
    __syncthreads();

    f32x4 rA0[MFRAG], rB0[MFRAG], rA1[MFRAG], rB1[MFRAG];
    // g0: a1 = relu(h) @ W1[0] + bb1[0]
    #pragma unroll
    for (int m = 0; m < MFRAG; m++) {
        rA0[m] = (f32x4){bvb1a0, bvb1a0, bvb1a0, bvb1a0};
        rA1[m] = (f32x4){bvb1a1, bvb1a1, bvb1a1, bvb1a1};
        rB0[m] = (f32x4){0.f, 0.f, 0.f, 0.f};
        rB1[m] = rB0[m];
    }
    {
        const bfrag* pa  = wtr + (((size_t)(e * 4 + 0) * 8 + nt0) * 4) * 128 + lane;
        const bfrag* pb  = wtr + (((size_t)(e * 4 + 0) * 8 + nt1) * 4) * 128 + lane;
        const bfrag* npa = wtr + (((size_t)(e * 4 + 1) * 8 + nt0) * 4) * 128 + lane;
        const bfrag* npb = wtr + (((size_t)(e * 4 + 1) * 8 + nt1) * 4) * 128 + lane;
        MFMA_STAGE(AH0, AL0, pa, pb, npa, npb, rA0, rB0, rA1, rB1);
    }
    #pragma unroll
    for (int m = 0; m < MFRAG; m++) { rA0[m] += rB0[m]; rA1[m] += rB1[m]; }
    WRITE_H(AH1, AL1, rA0, rA1);
    __syncthreads();

    // g1: h += relu(a1) @ W2[0] + bb2[0]
    #pragma unroll
    for (int m = 0; m < MFRAG; m++) {
        rA0[m] = (f32x4){bvb2a0, bvb2a0, bvb2a0, bvb2a0};
        rA1[m] = (f32x4){bvb2a1, bvb2a1, bvb2a1, bvb2a1};
        rB0[m] = (f32x4){0.f, 0.f, 0.f, 0.f};
        rB1[m] = rB0[m];
    }
    {
        const bfrag* pa  = wtr + (((size_t)(e * 4 + 1) * 8 + nt0) * 4) * 128 + lane;
        const bfrag* pb  = wtr + (((size_t)(e * 4 + 1) * 8 + nt1) * 4) * 128 + lane;
        const bfrag* npa = wtr + (((size_t)(e * 4 + 2) * 8 + nt0) * 4) * 128 + lane;
        const bfrag* npb = wtr + (((size_t)(e * 4 + 2) * 8 + nt1) * 4) * 128 + lane;
        MFMA_STAGE(AH1, AL1, pa, pb, npa, npb, rA0, rB0, rA1, rB1);
    }
    #pragma unroll
    for (int m = 0; m < MFRAG; m++) { h0[m] += rA0[m] + rB0[m]; h1[m] += rA1[m] + rB1[m]; }
    WRITE_H(AH0, AL0, h0, h1);
    __syncthreads();

    // g2: a1 = relu(h) @ W1[1] + bb1[1]
    #pragma unroll
    for (int m = 0; m < MFRAG; m++) {
        rA0[m] = (f32x4){bvb1b0, bvb1b0, bvb1b0, bvb1b0};
        rA1[m] = (f32x4){bvb1b1, bvb1b1, bvb1b1, bvb1b1};
        rB0[m] = (f32x4){0.f, 0.f, 0.f, 0.f};
        rB1[m] = rB0[m];
    }
    {
        const bfrag* pa  = wtr + (((size_t)(e * 4 + 2) * 8 + nt0) * 4) * 128 + lane;
        const bfrag* pb  = wtr + (((size_t)(e * 4 + 2) * 8 + nt1) * 4) * 128 + lane;
        const bfrag* npa = wtr + (((size_t)(e * 4 + 3) * 8 + nt0) * 4) * 128 + lane;
        const bfrag* npb = wtr + (((size_t)(e * 4 + 3) * 8 + nt1) * 4) * 128 + lane;
        MFMA_STAGE(AH0, AL0, pa, pb, npa, npb, rA0, rB0, rA1, rB1);
    }
    #pragma unroll
    for (int m = 0; m < MFRAG; m++) { rA0[m] += rB0[m]; rA1[m] += rB1[m]; }
    WRITE_H(AH1, AL1, rA0, rA1);
    __syncthreads();

    // g3: h += relu(a1) @ W2[1] + bb2[1]
    #pragma unroll
    for (int m = 0; m < MFRAG; m++) {
        rA0[m] = (f32x4){bvb2b0, bvb2b0, bvb2b0, bvb2b0};
        rA1[m] = (f32x4){bvb2b1, bvb2b1, bvb2b1, bvb2b1};
        rB0[m] = (f32x4){0.f, 0.f, 0.f, 0.f};
        rB1[m] = rB0[m];
    }
    {
        const bfrag* pa  = wtr + (((size_t)(e * 4 + 3) * 8 + nt0) * 4) * 128 + lane;
        const bfrag* pb  = wtr + (((size_t)(e * 4 + 3) * 8 + nt1) * 4) * 128 + lane;
        MFMA_STAGE(AH1, AL1, pa, pb, pa, pb, rA0, rB0, rA1, rB1);   // dummy next
    }
    #pragma unroll
    for (int m = 0; m < MFRAG; m++) { h0[m] += rA0[m] + rB0[m]; h1[m] += rA1[m] + rB1[m]; }

    // ---- epilogue: relu(h) fp32 -> Hf (buf0 region; g3 readers used buf1) ----
    #pragma unroll
    for (int m = 0; m < MFRAG; m++)
    {
        #pragma unroll
        for (int rr = 0; rr < 4; rr++) {
            int row = mrow + m * 16 + quad * 4 + rr;
            Hf[row][nc0] = fmaxf(h0[m][rr], 0.f);
            Hf[row][nc1] = fmaxf(h1[m][rr], 0.f);
        }
    }
    __syncthreads();

    // ---- out = relu(h) @ Wout + b_out (128 -> 14), 4-way partials ----
    const float* WoutE = Wout + (size_t)e * CH * (NANG * 2);
    const float* boutE = b_out + (size_t)e * (NANG * 2);
    for (int idx = t; idx < n * (NANG * 2); idx += TPB_MAIN) {
        int i = idx / (NANG * 2);
        int o = idx - i * (NANG * 2);
        float v0 = boutE[o], v1 = 0.f, v2 = 0.f, v3 = 0.f;
        #pragma unroll 4
        for (int k = 0; k < CH; k += 4) {
            v0 = fmaf(Hf[i][k],     WoutE[(size_t)k * (NANG * 2) + o],       v0);
            v1 = fmaf(Hf[i][k + 1], WoutE[(size_t)(k + 1) * (NANG * 2) + o], v1);
            v2 = fmaf(Hf[i][k + 2], WoutE[(size_t)(k + 2) * (NANG * 2) + o], v2);
            v3 = fmaf(Hf[i][k + 3], WoutE[(size_t)(k + 3) * (NANG * 2) + o], v3);
        }
        Of[i][o] = (v0 + v1) + (v2 + v3);
    }
    __syncthreads();

    // ---- pair-normalize and store ----
    for (int idx = t; idx < n * NANG; idx += TPB_MAIN) {
        int i = idx / NANG;
        int a = idx - i * NANG;
        float x = Of[i][2 * a];
        float y = Of[i][2 * a + 1];
        float nr = fmaxf(sqrtf(x * x + y * y), 1e-12f);
        size_t base = (size_t)ptok[i] * (NANG * 2) + 2 * a;
        out[base]     = x / nr;
        out[base + 1] = y / nr;
    }
}

extern "C" void kernel_launch(void* const* d_in, const int* in_sizes, int n_in,
                              void* d_out, int out_size, void* d_ws, size_t ws_size,
                              hipStream_t stream) {
    const float* s       = (const float*)d_in[0];
    const float* s_init  = (const float*)d_in[1];
    const int*   aatype  = (const int*)d_in[2];
    const float* Win     = (const float*)d_in[3];
    const float* b_in    = (const float*)d_in[4];
    const float* Winit   = (const float*)d_in[5];
    const float* b_init2 = (const float*)d_in[6];
    const float* Wb1     = (const float*)d_in[7];
    const float* bb1     = (const float*)d_in[8];
    const float* Wb2     = (const float*)d_in[9];
    const float* bb2     = (const float*)d_in[10];
    const float* Wout    = (const float*)d_in[11];
    const float* b_out   = (const float*)d_in[12];
    int* wsI = (int*)d_ws;
    unsigned short* wt = (unsigned short*)d_ws;
    float* out = (float*)d_out;

    hipLaunchKernelGGL(prep1, dim3(1664), dim3(256), 0, stream,
                       Win, Winit, Wb1, Wb2, aatype, wsI, wt);
    hipLaunchKernelGGL(angle_main, dim3(MAX_TILES), dim3(TPB_MAIN), 0, stream,
                       s, s_init, b_in, b_init2, bb1, bb2, Wout, b_out,
                       aatype, wsI, wt, out);
}

// Round 10
// 157.952 us; speedup vs baseline: 1.0518x; 1.0094x over previous
//
#include <hip/hip_runtime.h>
#include <math.h>

#define E_TYPES 20
#define NBLK 2
#define NANG 7
#define CS 384
#define CH 128
#define N_TOK (8 * 2048)
#define TOK 80
#define TPB_MAIN 1024
#define KC 128
#define MAX_TILES (N_TOK / TOK + E_TYPES)   // 204 + 20 = 224 (provable upper bound)
#define NPREP 64

// ---- workspace: int control region ----
#define HIST_OFF 0           // 64 x 20 per-block histograms

// ---- workspace: fragment-packed split-bf16 weights (bytes) ----
// 1KB block = 64 lanes x 16B; element (n,k): lane = (n&15)|((k>>3&3)<<4), j=k&7
#define WT1_OFF (256 * 1024)                       // phase-1 concat [768x128] per e
#define WT1_SZ  (20 * 8 * 24 * 2048)               // e x nt(8) x kb(24) x (hi1KB+lo1KB)
#define WTR_OFF (WT1_OFF + WT1_SZ)                 // residual: e x m4(4) x nt(8) x kb(4)
// total end ~13.4 MB

typedef __attribute__((ext_vector_type(8))) short bfrag;
typedef __attribute__((ext_vector_type(4))) float f32x4;
typedef unsigned short (*arr136)[136];

__device__ __forceinline__ void split_bf16(float x, unsigned short& h, unsigned short& l) {
    unsigned int u = __float_as_uint(x);
    unsigned int hb = (u + 0x7FFFu + ((u >> 16) & 1u)) & 0xFFFF0000u;
    h = (unsigned short)(hb >> 16);
    float r = x - __uint_as_float(hb);
    unsigned int v = __float_as_uint(r);
    l = (unsigned short)((v + 0x7FFFu + ((v >> 16) & 1u)) >> 16);
}

// prep1: blocks [0,1600) convert weights to fragment-packed split-bf16;
// blocks [1600,1664) build the per-block token histogram.
__global__ void prep1(const float* __restrict__ Win, const float* __restrict__ Winit,
                      const float* __restrict__ Wb1, const float* __restrict__ Wb2,
                      const int* __restrict__ aatype, int* __restrict__ wsI,
                      unsigned short* __restrict__ wt) {
    __shared__ int lh[E_TYPES];
    int bid = blockIdx.x;
    int t = threadIdx.x;
    if (bid >= 1600) {   // histogram part
        int b2 = bid - 1600;
        if (t < E_TYPES) lh[t] = 0;
        __syncthreads();
        int idx = b2 * 256 + t;
        if (idx < N_TOK) atomicAdd(&lh[aatype[idx]], 1);
        __syncthreads();
        if (t < E_TYPES) wsI[HIST_OFF + b2 * E_TYPES + t] = lh[t];
        return;
    }
    int gid = bid * 256 + t;
    unsigned short h[8], l[8];
    if (gid < 245760) {          // phase-1 weights: 20*8*24 blocks x 64 lanes
        int lane = gid & 63;
        int bi = gid >> 6;
        int kb = bi % 24;
        int r = bi / 24;
        int nt = r & 7, e = r >> 3;
        int n = nt * 16 + (lane & 15);
        int k0 = kb * 32 + (lane >> 4) * 8;
        #pragma unroll
        for (int j = 0; j < 8; j++) {
            int k = k0 + j;
            float x = (k < CS) ? Win[((size_t)e * CS + k) * CH + n]
                               : Winit[((size_t)e * CS + (k - CS)) * CH + n];
            split_bf16(x, h[j], l[j]);
        }
        unsigned short* dst = wt + (WT1_OFF / 2) + (size_t)bi * 1024 + lane * 8;
        *(bfrag*)dst = *(bfrag*)h;
        *(bfrag*)(dst + 512) = *(bfrag*)l;
    } else {                     // residual weights: 20*4*8*4 blocks x 64 lanes
        gid -= 245760;
        int lane = gid & 63;
        int bi = gid >> 6;       // 0..2559
        int kb = bi & 3;
        int nt = (bi >> 2) & 7;
        int m4 = (bi >> 5) & 3;
        int e = bi >> 7;
        int b = m4 >> 1;
        const float* W = (m4 & 1) ? Wb2 : Wb1;
        int n = nt * 16 + (lane & 15);
        int k0 = kb * 32 + (lane >> 4) * 8;
        #pragma unroll
        for (int j = 0; j < 8; j++) {
            int k = k0 + j;
            float x = W[(((size_t)e * NBLK + b) * CH + k) * CH + n];
            split_bf16(x, h[j], l[j]);
        }
        unsigned short* dst = wt + (WTR_OFF / 2) + (size_t)bi * 1024 + lane * 8;
        *(bfrag*)dst = *(bfrag*)h;
        *(bfrag*)(dst + 512) = *(bfrag*)l;
    }
}

#define MFMA(a, b, c) __builtin_amdgcn_mfma_f32_16x16x32_bf16((a), (b), (c), 0, 0, 0)

// One K=128 stage for MF m-frags starting at row MROW. Bd[PARITY] holds
// ks0/ks1 weights (prefetched across the barrier); ks2/ks3 loaded at
// entry; ks1 hook prefetches the NEXT stage's ks0/ks1 into Bd[1-PARITY].
#define STAGE_BODY(MF, MROW, WAH, WAL, PARITY, NEXTP, AA, BB, WBASE) do { \
    const bfrag* wbase_ = (WBASE);                                        \
    bfrag c2h = wbase_[256], c2l = wbase_[320];                           \
    bfrag c3h = wbase_[384], c3l = wbase_[448];                           \
    _Pragma("unroll")                                                     \
    for (int ks = 0; ks < 4; ks++) {                                      \
        bfrag bh = (ks == 0) ? Bd[PARITY][0] : (ks == 1) ? Bd[PARITY][1]  \
                  : (ks == 2) ? c2h : c3h;                                \
        bfrag bl = (ks == 0) ? Bd[PARITY][2] : (ks == 1) ? Bd[PARITY][3]  \
                  : (ks == 2) ? c2l : c3l;                                \
        int kl = ks * 32 + quad * 8;                                      \
        _Pragma("unroll")                                                 \
        for (int m = 0; m < MF; m++) {                                    \
            bfrag ah = *(const bfrag*)&WAH[(MROW) + m * 16 + lane15][kl]; \
            bfrag al = *(const bfrag*)&WAL[(MROW) + m * 16 + lane15][kl]; \
            AA[m] = MFMA(ah, bh, AA[m]);                                  \
            BB[m] = MFMA(ah, bl, BB[m]);                                  \
            BB[m] = MFMA(al, bh, BB[m]);                                  \
        }                                                                 \
        if (ks == 1) {                                                    \
            const bfrag* nb = (NEXTP);                                    \
            Bd[1 - (PARITY)][0] = nb[0];   Bd[1 - (PARITY)][1] = nb[128]; \
            Bd[1 - (PARITY)][2] = nb[64];  Bd[1 - (PARITY)][3] = nb[192]; \
        }                                                                 \
    }                                                                     \
} while (0)

// Write relu(SRC) (MF m-frags from MROW, C layout) as split-bf16 A.
#define WRITE_H_MF(MF, MROW, WAH, WAL, SRC) do {                   \
    _Pragma("unroll")                                              \
    for (int m = 0; m < MF; m++)                                   \
    {                                                              \
        _Pragma("unroll")                                          \
        for (int rr = 0; rr < 4; rr++) {                           \
            unsigned short hh, ll;                                 \
            split_bf16(fmaxf(SRC[m][rr], 0.f), hh, ll);            \
            WAH[(MROW) + m * 16 + quad * 4 + rr][nc] = hh;         \
            WAL[(MROW) + m * 16 + quad * 4 + rr][nc] = ll;         \
        }                                                          \
    }                                                              \
} while (0)

// Stage one 8-float activation segment (relu + split) into LDS.
__device__ __forceinline__ void stage_seg8(arr136 WAH, arr136 WAL, int row, int col,
                                           float4 a, float4 b) {
    float xv[8] = {a.x, a.y, a.z, a.w, b.x, b.y, b.z, b.w};
    unsigned short h8[8], l8[8];
    #pragma unroll
    for (int j = 0; j < 8; j++) split_bf16(fmaxf(xv[j], 0.f), h8[j], l8[j]);
    *(bfrag*)&WAH[row][col] = *(bfrag*)h8;
    *(bfrag*)&WAL[row][col] = *(bfrag*)l8;
}

// TOK=80, 1024 threads = 16 waves (8 n-groups x 2 m-groups; m split 3+2
// frags). Grid 224 = full fill AND 4 waves/SIMD (was 2) — doubles the
// instruction streams per SIMD to hide the ~50% no-issue stall cycles.
// Single barrier per stage (double-buffer proof: a buffer's last readers
// finished before the barrier 2 phases back). Activation prefetch issued
// AFTER the barrier (covered by MFMAs, not drained cold).
__global__ __launch_bounds__(TPB_MAIN, 4)
void angle_main(const float* __restrict__ s, const float* __restrict__ si,
                const float* __restrict__ b_in, const float* __restrict__ b_init2,
                const float* __restrict__ bb1, const float* __restrict__ bb2,
                const float* __restrict__ Wout, const float* __restrict__ b_out,
                const int* __restrict__ aatype,
                const int* __restrict__ wsI, const unsigned short* __restrict__ wt,
                float* __restrict__ out)
{
    // LDS pool: two (Ah,Al) buffers of [80][136] u16; epilogue Hf/Of overlap.
    #define ABUF 21760
    __shared__ __align__(16) char pool[4 * ABUF];
    __shared__ int ptok[TOK];
    __shared__ int cntS[E_TYPES];

    arr136 AH0 = (arr136)(pool);
    arr136 AL0 = (arr136)(pool + ABUF);
    arr136 AH1 = (arr136)(pool + 2 * ABUF);
    arr136 AL1 = (arr136)(pool + 3 * ABUF);
    float (*Hf)[132] = (float (*)[132])(pool);            // 80*132*4 = 42240 <= 2*ABUF
    float (*Of)[16]  = (float (*)[16])(pool + 2 * ABUF);  // 5KB

    int t = threadIdx.x;
    int w = t >> 6, lane = t & 63;
    int lane15 = lane & 15, quad = lane >> 4;
    int nw = w & 7;                 // n-group: 16 output cols
    int mg = w >> 3;                // m-group: 0 -> frags 0-2 (rows 0-47), 1 -> frags 3-4 (rows 48-79)
    int nc = nw * 16 + lane15;

    // XCD-chunked bijective swizzle (e-sorted tiles -> per-XCD L2 residency).
    int bid = blockIdx.x;
    const int q = MAX_TILES >> 3, r = MAX_TILES & 7;   // 28, 0
    int xcd = bid & 7, sub = bid >> 3;
    int tile = (xcd < r ? xcd * (q + 1) : r * (q + 1) + (xcd - r) * q) + sub;

    // wave0: per-type totals from the 64x20 chunk histograms
    if (w == 0 && lane < E_TYPES) {
        int c = 0;
        #pragma unroll
        for (int b = 0; b < NPREP; b++) c += wsI[HIST_OFF + b * E_TYPES + lane];
        cntS[lane] = c;
    }
    __syncthreads();

    int pos = tile * TOK;
    int e = -1, poff_e = 0;
    {
        int accT = 0;
        #pragma unroll
        for (int ee = 0; ee < E_TYPES; ee++) {
            int pad = ((cntS[ee] + TOK - 1) / TOK) * TOK;   // TOK not pow2
            if (e < 0 && pos < accT + pad) { e = ee; poff_e = accT; }
            accT += pad;
        }
        if (pos >= accT) return;     // uniform exit (all waves agree)
    }
    int pos_in = pos - poff_e;
    int n = cntS[e] - pos_in; if (n > TOK) n = TOK;

    const bfrag* wt1 = (const bfrag*)((const char*)wt + WT1_OFF);
    const bfrag* wtr = (const bfrag*)((const char*)wt + WTR_OFF);
    size_t wb = (size_t)(e * 8 + nw) * 24;

    // Early issue: stage-0 ks0/ks1 weights + all bias values.
    bfrag Bd[2][4];
    {
        const bfrag* nb = wt1 + wb * 128 + lane;
        Bd[0][0] = nb[0];   Bd[0][1] = nb[128];
        Bd[0][2] = nb[64];  Bd[0][3] = nb[192];
    }
    float bv_in  = b_in[e * CH + nc] + b_init2[e * CH + nc];
    float bvb1a = bb1[(e * NBLK + 0) * CH + nc];
    float bvb1b = bb1[(e * NBLK + 1) * CH + nc];
    float bvb2a = bb2[(e * NBLK + 0) * CH + nc];
    float bvb2b = bb2[(e * NBLK + 1) * CH + nc];

    // wave0: rank-scan aatype -> ptok (tokens with rank [pos_in, pos_in+n))
    if (w == 0) {
        int hb = wsI[HIST_OFF + lane * E_TYPES + e];
        int inc = hb;
        #pragma unroll
        for (int d = 1; d < 64; d <<= 1) { int v = __shfl_up(inc, d); if (lane >= d) inc += v; }
        int pre = inc - hb;
        unsigned long long mle = __ballot(pre <= pos_in);
        int cb = 63 - __clzll(mle);
        int running = __shfl(pre, cb);
        int base = cb * 256;
        int lim = pos_in + n;
        while (running < lim && base < N_TOK) {
            const int4 a4 = *(const int4*)&aatype[base + lane * 4];
            int m0 = (a4.x == e), m1 = (a4.y == e), m2 = (a4.z == e), m3 = (a4.w == e);
            int c = m0 + m1 + m2 + m3;
            int incl = c;
            #pragma unroll
            for (int d = 1; d < 64; d <<= 1) { int v = __shfl_up(incl, d); if (lane >= d) incl += v; }
            int rk = running + incl - c;
            int tk = base + lane * 4;
            if (m0) { if (rk >= pos_in && rk < lim) ptok[rk - pos_in] = tk;     rk++; }
            if (m1) { if (rk >= pos_in && rk < lim) ptok[rk - pos_in] = tk + 1; rk++; }
            if (m2) { if (rk >= pos_in && rk < lim) ptok[rk - pos_in] = tk + 2; rk++; }
            if (m3) { if (rk >= pos_in && rk < lim) ptok[rk - pos_in] = tk + 3; rk++; }
            running += __shfl(incl, 63);
            base += 256;
        }
        int t0v = ptok[0];
        for (int i = n + lane; i < TOK; i += 64) ptok[i] = t0v;   // pad w/ dup token
    }
    __syncthreads();

    // ---- phase 1: h = [relu(s) relu(si)] @ [Win;Winit] + biases, K=768 ----
    // Staging: 16 threads/row x 8 floats; rows 0-63 by all 1024 threads,
    // rows 64-79 second seg on threads 0-255 (waves 0-3, uniform).
    int srow0 = t >> 4;
    int scol0 = (t & 15) * 8;
    bool has2 = (t < 256);
    int srow1 = 64 + (t >> 4);               // valid only when has2
    size_t ro0 = (size_t)ptok[srow0] * CS + scol0;
    size_t ro1 = has2 ? ((size_t)ptok[srow1] * CS + scol0) : ro0;
    float4 p0 = *(const float4*)(s + ro0);
    float4 p1 = *(const float4*)(s + ro0 + 4);
    float4 q0, q1;
    if (has2) {
        q0 = *(const float4*)(s + ro1);
        q1 = *(const float4*)(s + ro1 + 4);
    }

    f32x4 aA[3], aB[3];
    #pragma unroll
    for (int m = 0; m < 3; m++) {
        aA[m] = (f32x4){bv_in, bv_in, bv_in, bv_in};
        aB[m] = (f32x4){0.f, 0.f, 0.f, 0.f};
    }

    #pragma unroll
    for (int c = 0; c < 6; c++) {
        arr136 WAH = (c & 1) ? AH1 : AH0;
        arr136 WAL = (c & 1) ? AL1 : AL0;
        stage_seg8(WAH, WAL, srow0, scol0, p0, p1);
        if (has2) stage_seg8(WAH, WAL, srow1, scol0, q0, q1);
        __syncthreads();
        if (c < 5) {   // issue next-chunk loads AFTER the barrier (MFMA cover)
            const float* src = (c + 1 < 3) ? s : si;
            int kb0 = ((c + 1 < 3) ? (c + 1) : (c - 2)) * KC;
            p0 = *(const float4*)(src + ro0 + kb0);
            p1 = *(const float4*)(src + ro0 + kb0 + 4);
            if (has2) {
                q0 = *(const float4*)(src + ro1 + kb0);
                q1 = *(const float4*)(src + ro1 + kb0 + 4);
            }
        }
        const bfrag* wbase = wt1 + (wb + c * 4) * 128 + lane;
        const bfrag* nextp = (c < 5)
            ? wt1 + (wb + (c + 1) * 4) * 128 + lane
            : wtr + (((size_t)(e * 4) * 8 + nw) * 4) * 128 + lane;
        if (mg == 0) STAGE_BODY(3, 0,  WAH, WAL, (c & 1), nextp, aA, aB, wbase);
        else         STAGE_BODY(2, 48, WAH, WAL, (c & 1), nextp, aA, aB, wbase);
        // no trailing barrier: next stage writes the other buffer, whose
        // readers (stage c-1) all finished before this stage's barrier.
    }

    // ---- residual blocks: 4 GEMMs, one barrier each ----
    f32x4 h[3];
    #pragma unroll
    for (int m = 0; m < 3; m++) h[m] = aA[m] + aB[m];
    if (mg == 0) WRITE_H_MF(3, 0,  AH0, AL0, h);
    else         WRITE_H_MF(2, 48, AH0, AL0, h);
    __syncthreads();

    f32x4 rA[3], rB[3];
    #pragma unroll
    for (int g = 0; g < 4; g++) {
        float bv = (g == 0) ? bvb1a : (g == 1) ? bvb2a : (g == 2) ? bvb1b : bvb2b;
        #pragma unroll
        for (int m = 0; m < 3; m++) {
            rA[m] = (f32x4){bv, bv, bv, bv};
            rB[m] = (f32x4){0.f, 0.f, 0.f, 0.f};
        }
        arr136 WAH = (g & 1) ? AH1 : AH0;
        arr136 WAL = (g & 1) ? AL1 : AL0;
        const bfrag* wbase = wtr + (((size_t)(e * 4 + g) * 8 + nw) * 4) * 128 + lane;
        const bfrag* nextp = (g < 3)
            ? wtr + (((size_t)(e * 4 + g + 1) * 8 + nw) * 4) * 128 + lane
            : wbase;   // dummy (unused next stage)
        if (mg == 0) STAGE_BODY(3, 0,  WAH, WAL, (g & 1), nextp, rA, rB, wbase);
        else         STAGE_BODY(2, 48, WAH, WAL, (g & 1), nextp, rA, rB, wbase);
        if (g & 1) {   // end of a residual block: h += W2 out
            #pragma unroll
            for (int m = 0; m < 3; m++) h[m] += rA[m] + rB[m];
            if (g < 3) {
                if (mg == 0) WRITE_H_MF(3, 0,  AH0, AL0, h);
                else         WRITE_H_MF(2, 48, AH0, AL0, h);
                __syncthreads();
            }
        } else {       // mid-block: a1 = relu-input for W2
            #pragma unroll
            for (int m = 0; m < 3; m++) rA[m] += rB[m];
            if (mg == 0) WRITE_H_MF(3, 0,  AH1, AL1, rA);
            else         WRITE_H_MF(2, 48, AH1, AL1, rA);
            __syncthreads();
        }
    }

    // ---- epilogue: relu(h) fp32 -> Hf (buf0 region; g3 read buf1) ----
    {
        int mrow = mg ? 48 : 0;
        int mf = mg ? 2 : 3;
        if (mg == 0) {
            #pragma unroll
            for (int m = 0; m < 3; m++)
                #pragma unroll
                for (int rr = 0; rr < 4; rr++)
                    Hf[m * 16 + quad * 4 + rr][nc] = fmaxf(h[m][rr], 0.f);
        } else {
            #pragma unroll
            for (int m = 0; m < 2; m++)
                #pragma unroll
                for (int rr = 0; rr < 4; rr++)
                    Hf[48 + m * 16 + quad * 4 + rr][nc] = fmaxf(h[m][rr], 0.f);
        }
        (void)mrow; (void)mf;
    }
    __syncthreads();

    // ---- out = relu(h) @ Wout + b_out (128 -> 14), 4-way partials ----
    const float* WoutE = Wout + (size_t)e * CH * (NANG * 2);
    const float* boutE = b_out + (size_t)e * (NANG * 2);
    for (int idx = t; idx < n * (NANG * 2); idx += TPB_MAIN) {
        int i = idx / (NANG * 2);
        int o = idx - i * (NANG * 2);
        float v0 = boutE[o], v1 = 0.f, v2 = 0.f, v3 = 0.f;
        #pragma unroll 4
        for (int k = 0; k < CH; k += 4) {
            v0 = fmaf(Hf[i][k],     WoutE[(size_t)k * (NANG * 2) + o],       v0);
            v1 = fmaf(Hf[i][k + 1], WoutE[(size_t)(k + 1) * (NANG * 2) + o], v1);
            v2 = fmaf(Hf[i][k + 2], WoutE[(size_t)(k + 2) * (NANG * 2) + o], v2);
            v3 = fmaf(Hf[i][k + 3], WoutE[(size_t)(k + 3) * (NANG * 2) + o], v3);
        }
        Of[i][o] = (v0 + v1) + (v2 + v3);
    }
    __syncthreads();

    // ---- pair-normalize and store ----
    for (int idx = t; idx < n * NANG; idx += TPB_MAIN) {
        int i = idx / NANG;
        int a = idx - i * NANG;
        float x = Of[i][2 * a];
        float y = Of[i][2 * a + 1];
        float nr = fmaxf(sqrtf(x * x + y * y), 1e-12f);
        size_t base = (size_t)ptok[i] * (NANG * 2) + 2 * a;
        out[base]     = x / nr;
        out[base + 1] = y / nr;
    }
}

extern "C" void kernel_launch(void* const* d_in, const int* in_sizes, int n_in,
                              void* d_out, int out_size, void* d_ws, size_t ws_size,
                              hipStream_t stream) {
    const float* s       = (const float*)d_in[0];
    const float* s_init  = (const float*)d_in[1];
    const int*   aatype  = (const int*)d_in[2];
    const float* Win     = (const float*)d_in[3];
    const float* b_in    = (const float*)d_in[4];
    const float* Winit   = (const float*)d_in[5];
    const float* b_init2 = (const float*)d_in[6];
    const float* Wb1     = (const float*)d_in[7];
    const float* bb1     = (const float*)d_in[8];
    const float* Wb2     = (const float*)d_in[9];
    const float* bb2     = (const float*)d_in[10];
    const float* Wout    = (const float*)d_in[11];
    const float* b_out   = (const float*)d_in[12];
    int* wsI = (int*)d_ws;
    unsigned short* wt = (unsigned short*)d_ws;
    float* out = (float*)d_out;

    hipLaunchKernelGGL(prep1, dim3(1664), dim3(256), 0, stream,
                       Win, Winit, Wb1, Wb2, aatype, wsI, wt);
    hipLaunchKernelGGL(angle_main, dim3(MAX_TILES), dim3(TPB_MAIN), 0, stream,
                       s, s_init, b_in, b_init2, bb1, bb2, Wout, b_out,
                       aatype, wsI, wt, out);
}

// Round 11
// 152.060 us; speedup vs baseline: 1.0925x; 1.0387x over previous
//
#include <hip/hip_runtime.h>
#include <math.h>

#define E_TYPES 20
#define NBLK 2
#define NANG 7
#define CS 384
#define CH 128
#define N_TOK (8 * 2048)
#define TOK 80
#define MFRAG 5
#define TPB_MAIN 512
#define KC 128
#define MAX_TILES (N_TOK / TOK + E_TYPES)   // 204 + 20 = 224 (provable upper bound)
#define NPREP 64

// ---- workspace: int control region ----
#define HIST_OFF 0           // 64 x 20 per-block histograms

// ---- workspace: fragment-packed split-bf16 weights (bytes) ----
// 1KB block = 64 lanes x 16B; element (n,k): lane = (n&15)|((k>>3&3)<<4), j=k&7
#define WT1_OFF (256 * 1024)                       // phase-1 concat [768x128] per e
#define WT1_SZ  (20 * 8 * 24 * 2048)               // e x nt(8) x kb(24) x (hi1KB+lo1KB)
#define WTR_OFF (WT1_OFF + WT1_SZ)                 // residual: e x m4(4) x nt(8) x kb(4)
// total end ~13.4 MB

typedef __attribute__((ext_vector_type(8))) short bfrag;
typedef __attribute__((ext_vector_type(4))) float f32x4;
typedef unsigned short (*arr136)[136];

__device__ __forceinline__ void split_bf16(float x, unsigned short& h, unsigned short& l) {
    unsigned int u = __float_as_uint(x);
    unsigned int hb = (u + 0x7FFFu + ((u >> 16) & 1u)) & 0xFFFF0000u;
    h = (unsigned short)(hb >> 16);
    float r = x - __uint_as_float(hb);
    unsigned int v = __float_as_uint(r);
    l = (unsigned short)((v + 0x7FFFu + ((v >> 16) & 1u)) >> 16);
}

// prep1: blocks [0,1600) convert weights to fragment-packed split-bf16;
// blocks [1600,1664) build the per-block token histogram.
__global__ void prep1(const float* __restrict__ Win, const float* __restrict__ Winit,
                      const float* __restrict__ Wb1, const float* __restrict__ Wb2,
                      const int* __restrict__ aatype, int* __restrict__ wsI,
                      unsigned short* __restrict__ wt) {
    __shared__ int lh[E_TYPES];
    int bid = blockIdx.x;
    int t = threadIdx.x;
    if (bid >= 1600) {   // histogram part
        int b2 = bid - 1600;
        if (t < E_TYPES) lh[t] = 0;
        __syncthreads();
        int idx = b2 * 256 + t;
        if (idx < N_TOK) atomicAdd(&lh[aatype[idx]], 1);
        __syncthreads();
        if (t < E_TYPES) wsI[HIST_OFF + b2 * E_TYPES + t] = lh[t];
        return;
    }
    int gid = bid * 256 + t;
    unsigned short h[8], l[8];
    if (gid < 245760) {          // phase-1 weights: 20*8*24 blocks x 64 lanes
        int lane = gid & 63;
        int bi = gid >> 6;
        int kb = bi % 24;
        int r = bi / 24;
        int nt = r & 7, e = r >> 3;
        int n = nt * 16 + (lane & 15);
        int k0 = kb * 32 + (lane >> 4) * 8;
        #pragma unroll
        for (int j = 0; j < 8; j++) {
            int k = k0 + j;
            float x = (k < CS) ? Win[((size_t)e * CS + k) * CH + n]
                               : Winit[((size_t)e * CS + (k - CS)) * CH + n];
            split_bf16(x, h[j], l[j]);
        }
        unsigned short* dst = wt + (WT1_OFF / 2) + (size_t)bi * 1024 + lane * 8;
        *(bfrag*)dst = *(bfrag*)h;
        *(bfrag*)(dst + 512) = *(bfrag*)l;
    } else {                     // residual weights: 20*4*8*4 blocks x 64 lanes
        gid -= 245760;
        int lane = gid & 63;
        int bi = gid >> 6;       // 0..2559
        int kb = bi & 3;
        int nt = (bi >> 2) & 7;
        int m4 = (bi >> 5) & 3;
        int e = bi >> 7;
        int b = m4 >> 1;
        const float* W = (m4 & 1) ? Wb2 : Wb1;
        int n = nt * 16 + (lane & 15);
        int k0 = kb * 32 + (lane >> 4) * 8;
        #pragma unroll
        for (int j = 0; j < 8; j++) {
            int k = k0 + j;
            float x = W[(((size_t)e * NBLK + b) * CH + k) * CH + n];
            split_bf16(x, h[j], l[j]);
        }
        unsigned short* dst = wt + (WTR_OFF / 2) + (size_t)bi * 1024 + lane * 8;
        *(bfrag*)dst = *(bfrag*)h;
        *(bfrag*)(dst + 512) = *(bfrag*)l;
    }
}

#define MFMA(a, b, c) __builtin_amdgcn_mfma_f32_16x16x32_bf16((a), (b), (c), 0, 0, 0)

// Load the 8 weight fragments (bh ks0..3, bl ks0..3) for one stage.
#define LOADW(DST, BASEPTR) do {                                   \
    const bfrag* _p = (BASEPTR);                                   \
    DST[0] = _p[0];   DST[1] = _p[128];                            \
    DST[2] = _p[256]; DST[3] = _p[384];                            \
    DST[4] = _p[64];  DST[5] = _p[192];                            \
    DST[6] = _p[320]; DST[7] = _p[448];                            \
} while (0)

// One K=128 stage, register-pipelined: batch-load all 10 A-fragments of
// k-slice ks into a double-buffered reg array, issuing slice ks+1's reads
// BEFORE slice ks's 15 MFMAs. All indices compile-time after unroll.
#define MFMA_STAGE(WAH, WAL, CUR, AA, BB) do {                     \
    bfrag fh[2][MFRAG], fl[2][MFRAG];                              \
    _Pragma("unroll")                                              \
    for (int m = 0; m < MFRAG; m++) {                              \
        fh[0][m] = *(const bfrag*)&WAH[m * 16 + lane15][quad * 8]; \
        fl[0][m] = *(const bfrag*)&WAL[m * 16 + lane15][quad * 8]; \
    }                                                              \
    _Pragma("unroll")                                              \
    for (int ks = 0; ks < 4; ks++) {                               \
        if (ks < 3) {                                              \
            int nkl = (ks + 1) * 32 + quad * 8;                    \
            _Pragma("unroll")                                      \
            for (int m = 0; m < MFRAG; m++) {                      \
                fh[(ks + 1) & 1][m] = *(const bfrag*)&WAH[m * 16 + lane15][nkl]; \
                fl[(ks + 1) & 1][m] = *(const bfrag*)&WAL[m * 16 + lane15][nkl]; \
            }                                                      \
        }                                                          \
        _Pragma("unroll")                                          \
        for (int m = 0; m < MFRAG; m++) {                          \
            AA[m] = MFMA(fh[ks & 1][m], CUR[ks], AA[m]);           \
            BB[m] = MFMA(fh[ks & 1][m], CUR[4 + ks], BB[m]);       \
            BB[m] = MFMA(fl[ks & 1][m], CUR[ks], BB[m]);           \
        }                                                          \
    }                                                              \
} while (0)

// Write relu(SRC) (MFRAG m-frags, C layout) as split-bf16 A for next GEMM.
#define WRITE_H(WAH, WAL, SRC) do {                                \
    _Pragma("unroll")                                              \
    for (int m = 0; m < MFRAG; m++)                                \
    {                                                              \
        _Pragma("unroll")                                          \
        for (int rr = 0; rr < 4; rr++) {                           \
            unsigned short hh, ll;                                 \
            split_bf16(fmaxf(SRC[m][rr], 0.f), hh, ll);            \
            WAH[m * 16 + quad * 4 + rr][nc] = hh;                  \
            WAL[m * 16 + quad * 4 + rr][nc] = ll;                  \
        }                                                          \
    }                                                              \
} while (0)

// Stage one 16-float activation segment (relu + split) into LDS.
__device__ __forceinline__ void stage_seg(arr136 WAH, arr136 WAL, int row, int col,
                                          float4 a, float4 b, float4 c, float4 d) {
    float xv[16] = {a.x, a.y, a.z, a.w, b.x, b.y, b.z, b.w,
                    c.x, c.y, c.z, c.w, d.x, d.y, d.z, d.w};
    unsigned short h8[8], l8[8];
    #pragma unroll
    for (int j = 0; j < 8; j++) split_bf16(fmaxf(xv[j], 0.f), h8[j], l8[j]);
    *(bfrag*)&WAH[row][col] = *(bfrag*)h8;
    *(bfrag*)&WAL[row][col] = *(bfrag*)l8;
    #pragma unroll
    for (int j = 0; j < 8; j++) split_bf16(fmaxf(xv[8 + j], 0.f), h8[j], l8[j]);
    *(bfrag*)&WAH[row][col + 8] = *(bfrag*)h8;
    *(bfrag*)&WAL[row][col + 8] = *(bfrag*)l8;
}

// TOK=80 (5 m-frags): tile count <= 224 <= 256 for ANY type distribution,
// so every block runs in the first (and only) wave of blocks per CU.
__global__ __launch_bounds__(TPB_MAIN, 2)
void angle_main(const float* __restrict__ s, const float* __restrict__ si,
                const float* __restrict__ b_in, const float* __restrict__ b_init2,
                const float* __restrict__ bb1, const float* __restrict__ bb2,
                const float* __restrict__ Wout, const float* __restrict__ b_out,
                const int* __restrict__ aatype,
                const int* __restrict__ wsI, const unsigned short* __restrict__ wt,
                float* __restrict__ out)
{
    // LDS pool: two (Ah,Al) buffers of [80][136] u16; epilogue Hf/Of overlap.
    #define ABUF 21760
    __shared__ __align__(16) char pool[4 * ABUF];
    __shared__ int ptok[TOK];
    __shared__ int cntS[E_TYPES];

    arr136 AH0 = (arr136)(pool);
    arr136 AL0 = (arr136)(pool + ABUF);
    arr136 AH1 = (arr136)(pool + 2 * ABUF);
    arr136 AL1 = (arr136)(pool + 3 * ABUF);
    float (*Hf)[132] = (float (*)[132])(pool);            // 80*132*4 = 42240 <= 2*ABUF
    float (*Of)[16]  = (float (*)[16])(pool + 2 * ABUF);  // 5KB

    int t = threadIdx.x;
    int w = t >> 6, lane = t & 63;
    int lane15 = lane & 15, quad = lane >> 4;

    // XCD-chunked bijective swizzle (e-sorted tiles -> per-XCD L2 residency).
    int bid = blockIdx.x;
    const int q = MAX_TILES >> 3, r = MAX_TILES & 7;   // 28, 0
    int xcd = bid & 7, sub = bid >> 3;
    int tile = (xcd < r ? xcd * (q + 1) : r * (q + 1) + (xcd - r) * q) + sub;

    // wave0: per-type totals from the 64x20 chunk histograms
    if (w == 0 && lane < E_TYPES) {
        int c = 0;
        #pragma unroll
        for (int b = 0; b < NPREP; b++) c += wsI[HIST_OFF + b * E_TYPES + lane];
        cntS[lane] = c;
    }
    __syncthreads();

    int pos = tile * TOK;
    int e = -1, poff_e = 0;
    {
        int accT = 0;
        #pragma unroll
        for (int ee = 0; ee < E_TYPES; ee++) {
            int pad = ((cntS[ee] + TOK - 1) / TOK) * TOK;   // TOK not pow2
            if (e < 0 && pos < accT + pad) { e = ee; poff_e = accT; }
            accT += pad;
        }
        if (pos >= accT) return;     // uniform exit (all waves agree)
    }
    int pos_in = pos - poff_e;
    int n = cntS[e] - pos_in; if (n > TOK) n = TOK;

    int nc = w * 16 + lane15;
    const bfrag* wt1 = (const bfrag*)((const char*)wt + WT1_OFF);
    const bfrag* wtr = (const bfrag*)((const char*)wt + WTR_OFF);
    size_t wb = (size_t)(e * 8 + w) * 24;

    // Early issue: stage-0 weights + all bias values (overlap the rank-scan).
    bfrag Wr0[8], Wr1[8];
    LOADW(Wr0, wt1 + wb * 128 + lane);
    float bv_in = b_in[e * CH + nc] + b_init2[e * CH + nc];
    float bvb1a = bb1[(e * NBLK + 0) * CH + nc];
    float bvb1b = bb1[(e * NBLK + 1) * CH + nc];
    float bvb2a = bb2[(e * NBLK + 0) * CH + nc];
    float bvb2b = bb2[(e * NBLK + 1) * CH + nc];

    // wave0: rank-scan aatype -> ptok (tokens with rank [pos_in, pos_in+n))
    if (w == 0) {
        int hb = wsI[HIST_OFF + lane * E_TYPES + e];
        int inc = hb;
        #pragma unroll
        for (int d = 1; d < 64; d <<= 1) { int v = __shfl_up(inc, d); if (lane >= d) inc += v; }
        int pre = inc - hb;
        unsigned long long mle = __ballot(pre <= pos_in);
        int cb = 63 - __clzll(mle);
        int running = __shfl(pre, cb);
        int base = cb * 256;
        int lim = pos_in + n;
        while (running < lim && base < N_TOK) {
            const int4 a4 = *(const int4*)&aatype[base + lane * 4];
            int m0 = (a4.x == e), m1 = (a4.y == e), m2 = (a4.z == e), m3 = (a4.w == e);
            int c = m0 + m1 + m2 + m3;
            int incl = c;
            #pragma unroll
            for (int d = 1; d < 64; d <<= 1) { int v = __shfl_up(incl, d); if (lane >= d) incl += v; }
            int rk = running + incl - c;
            int tk = base + lane * 4;
            if (m0) { if (rk >= pos_in && rk < lim) ptok[rk - pos_in] = tk;     rk++; }
            if (m1) { if (rk >= pos_in && rk < lim) ptok[rk - pos_in] = tk + 1; rk++; }
            if (m2) { if (rk >= pos_in && rk < lim) ptok[rk - pos_in] = tk + 2; rk++; }
            if (m3) { if (rk >= pos_in && rk < lim) ptok[rk - pos_in] = tk + 3; rk++; }
            running += __shfl(incl, 63);
            base += 256;
        }
        int t0v = ptok[0];
        for (int i = n + lane; i < TOK; i += 64) ptok[i] = t0v;   // pad w/ dup token
    }
    __syncthreads();

    // ---- phase 1: h = [relu(s) relu(si)] @ [Win;Winit] + biases, K=768 ----
    // Staging: 640 segs (80 rows x 8) over 512 threads; waves 0-1 take a
    // second seg (wave-uniform). One chunk prefetched ahead in regs.
    int srow0 = t >> 3;
    int scol0 = (t & 7) * 16;
    bool has2 = (t < TOK * 8 - TPB_MAIN);    // t < 128
    int srow1 = srow0 + 64;
    size_t ro0 = (size_t)ptok[srow0] * CS + scol0;
    size_t ro1 = has2 ? ((size_t)ptok[srow1] * CS + scol0) : ro0;
    float4 p0 = *(const float4*)(s + ro0);
    float4 p1 = *(const float4*)(s + ro0 + 4);
    float4 p2 = *(const float4*)(s + ro0 + 8);
    float4 p3 = *(const float4*)(s + ro0 + 12);
    float4 q0, q1, q2, q3;
    if (has2) {
        q0 = *(const float4*)(s + ro1);
        q1 = *(const float4*)(s + ro1 + 4);
        q2 = *(const float4*)(s + ro1 + 8);
        q3 = *(const float4*)(s + ro1 + 12);
    }

    f32x4 aA[MFRAG], aB[MFRAG];
    #pragma unroll
    for (int m = 0; m < MFRAG; m++) {
        aA[m] = (f32x4){bv_in, bv_in, bv_in, bv_in};
        aB[m] = (f32x4){0.f, 0.f, 0.f, 0.f};
    }

    #pragma unroll
    for (int c = 0; c < 6; c++) {
        arr136 WAH = (c & 1) ? AH1 : AH0;
        arr136 WAL = (c & 1) ? AL1 : AL0;
        stage_seg(WAH, WAL, srow0, scol0, p0, p1, p2, p3);
        if (has2) stage_seg(WAH, WAL, srow1, scol0, q0, q1, q2, q3);
        if (c < 5) {   // prefetch next chunk activations
            const float* src = (c + 1 < 3) ? s : si;
            int kb0 = ((c + 1 < 3) ? (c + 1) : (c - 2)) * KC;
            p0 = *(const float4*)(src + ro0 + kb0);
            p1 = *(const float4*)(src + ro0 + kb0 + 4);
            p2 = *(const float4*)(src + ro0 + kb0 + 8);
            p3 = *(const float4*)(src + ro0 + kb0 + 12);
            if (has2) {
                q0 = *(const float4*)(src + ro1 + kb0);
                q1 = *(const float4*)(src + ro1 + kb0 + 4);
                q2 = *(const float4*)(src + ro1 + kb0 + 8);
                q3 = *(const float4*)(src + ro1 + kb0 + 12);
            }
        }
        __syncthreads();
        if ((c & 1) == 0) {
            if (c < 5) LOADW(Wr1, wt1 + (wb + (c + 1) * 4) * 128 + lane);
            MFMA_STAGE(AH0, AL0, Wr0, aA, aB);
        } else {
            if (c == 5) LOADW(Wr0, wtr + (((size_t)(e * 4) * 8 + w) * 4) * 128 + lane);
            else        LOADW(Wr0, wt1 + (wb + (c + 1) * 4) * 128 + lane);
            MFMA_STAGE(AH1, AL1, Wr1, aA, aB);
        }
    }

    // ---- residual blocks: 4 GEMMs, one barrier each ----
    f32x4 h[MFRAG];
    #pragma unroll
    for (int m = 0; m < MFRAG; m++) h[m] = aA[m] + aB[m];
    WRITE_H(AH0, AL0, h);
    __syncthreads();

    f32x4 rA[MFRAG], rB[MFRAG];
    // g0: a1 = relu(h) @ W1[0] + bb1[0]
    #pragma unroll
    for (int m = 0; m < MFRAG; m++) {
        rA[m] = (f32x4){bvb1a, bvb1a, bvb1a, bvb1a};
        rB[m] = (f32x4){0.f, 0.f, 0.f, 0.f};
    }
    LOADW(Wr1, wtr + (((size_t)(e * 4 + 1) * 8 + w) * 4) * 128 + lane);
    MFMA_STAGE(AH0, AL0, Wr0, rA, rB);
    #pragma unroll
    for (int m = 0; m < MFRAG; m++) rA[m] += rB[m];
    WRITE_H(AH1, AL1, rA);
    __syncthreads();

    // g1: h += relu(a1) @ W2[0] + bb2[0]
    #pragma unroll
    for (int m = 0; m < MFRAG; m++) {
        rA[m] = (f32x4){bvb2a, bvb2a, bvb2a, bvb2a};
        rB[m] = (f32x4){0.f, 0.f, 0.f, 0.f};
    }
    LOADW(Wr0, wtr + (((size_t)(e * 4 + 2) * 8 + w) * 4) * 128 + lane);
    MFMA_STAGE(AH1, AL1, Wr1, rA, rB);
    #pragma unroll
    for (int m = 0; m < MFRAG; m++) h[m] += rA[m] + rB[m];
    WRITE_H(AH0, AL0, h);
    __syncthreads();

    // g2: a1 = relu(h) @ W1[1] + bb1[1]
    #pragma unroll
    for (int m = 0; m < MFRAG; m++) {
        rA[m] = (f32x4){bvb1b, bvb1b, bvb1b, bvb1b};
        rB[m] = (f32x4){0.f, 0.f, 0.f, 0.f};
    }
    LOADW(Wr1, wtr + (((size_t)(e * 4 + 3) * 8 + w) * 4) * 128 + lane);
    MFMA_STAGE(AH0, AL0, Wr0, rA, rB);
    #pragma unroll
    for (int m = 0; m < MFRAG; m++) rA[m] += rB[m];
    WRITE_H(AH1, AL1, rA);
    __syncthreads();

    // g3: h += relu(a1) @ W2[1] + bb2[1]
    #pragma unroll
    for (int m = 0; m < MFRAG; m++) {
        rA[m] = (f32x4){bvb2b, bvb2b, bvb2b, bvb2b};
        rB[m] = (f32x4){0.f, 0.f, 0.f, 0.f};
    }
    MFMA_STAGE(AH1, AL1, Wr1, rA, rB);
    #pragma unroll
    for (int m = 0; m < MFRAG; m++) h[m] += rA[m] + rB[m];

    // ---- epilogue: relu(h) fp32 -> Hf (buf0 region; g3 readers used buf1) ----
    #pragma unroll
    for (int m = 0; m < MFRAG; m++)
    {
        #pragma unroll
        for (int rr = 0; rr < 4; rr++)
            Hf[m * 16 + quad * 4 + rr][nc] = fmaxf(h[m][rr], 0.f);
    }
    __syncthreads();

    // ---- out = relu(h) @ Wout + b_out (128 -> 14), 4-way partials ----
    const float* WoutE = Wout + (size_t)e * CH * (NANG * 2);
    const float* boutE = b_out + (size_t)e * (NANG * 2);
    for (int idx = t; idx < n * (NANG * 2); idx += TPB_MAIN) {
        int i = idx / (NANG * 2);
        int o = idx - i * (NANG * 2);
        float v0 = boutE[o], v1 = 0.f, v2 = 0.f, v3 = 0.f;
        #pragma unroll 4
        for (int k = 0; k < CH; k += 4) {
            v0 = fmaf(Hf[i][k],     WoutE[(size_t)k * (NANG * 2) + o],       v0);
            v1 = fmaf(Hf[i][k + 1], WoutE[(size_t)(k + 1) * (NANG * 2) + o], v1);
            v2 = fmaf(Hf[i][k + 2], WoutE[(size_t)(k + 2) * (NANG * 2) + o], v2);
            v3 = fmaf(Hf[i][k + 3], WoutE[(size_t)(k + 3) * (NANG * 2) + o], v3);
        }
        Of[i][o] = (v0 + v1) + (v2 + v3);
    }
    __syncthreads();

    // ---- pair-normalize and store ----
    for (int idx = t; idx < n * NANG; idx += TPB_MAIN) {
        int i = idx / NANG;
        int a = idx - i * NANG;
        float x = Of[i][2 * a];
        float y = Of[i][2 * a + 1];
        float nr = fmaxf(sqrtf(x * x + y * y), 1e-12f);
        size_t base = (size_t)ptok[i] * (NANG * 2) + 2 * a;
        out[base]     = x / nr;
        out[base + 1] = y / nr;
    }
}

extern "C" void kernel_launch(void* const* d_in, const int* in_sizes, int n_in,
                              void* d_out, int out_size, void* d_ws, size_t ws_size,
                              hipStream_t stream) {
    const float* s       = (const float*)d_in[0];
    const float* s_init  = (const float*)d_in[1];
    const int*   aatype  = (const int*)d_in[2];
    const float* Win     = (const float*)d_in[3];
    const float* b_in    = (const float*)d_in[4];
    const float* Winit   = (const float*)d_in[5];
    const float* b_init2 = (const float*)d_in[6];
    const float* Wb1     = (const float*)d_in[7];
    const float* bb1     = (const float*)d_in[8];
    const float* Wb2     = (const float*)d_in[9];
    const float* bb2     = (const float*)d_in[10];
    const float* Wout    = (const float*)d_in[11];
    const float* b_out   = (const float*)d_in[12];
    int* wsI = (int*)d_ws;
    unsigned short* wt = (unsigned short*)d_ws;
    float* out = (float*)d_out;

    hipLaunchKernelGGL(prep1, dim3(1664), dim3(256), 0, stream,
                       Win, Winit, Wb1, Wb2, aatype, wsI, wt);
    hipLaunchKernelGGL(angle_main, dim3(MAX_TILES), dim3(TPB_MAIN), 0, stream,
                       s, s_init, b_in, b_init2, bb1, bb2, Wout, b_out,
                       aatype, wsI, wt, out);
}